// Round 1
// baseline (2438.423 us; speedup 1.0000x reference)
//
#include <hip/hip_runtime.h>
#include <hip/hip_bf16.h>

#define N_NODES 50000
#define N_EDGES 800000

// ---------- helpers ----------
__device__ __forceinline__ unsigned f2ord(float f) {
    unsigned u = __float_as_uint(f);
    return (u & 0x80000000u) ? ~u : (u | 0x80000000u);
}
__device__ __forceinline__ float ord2f(unsigned u) {
    return (u & 0x80000000u) ? __uint_as_float(u & 0x7fffffffu) : __uint_as_float(~u);
}
// full 64-lane butterfly sum of 4 values; every lane ends with the totals
__device__ __forceinline__ void bsum4(float& v0, float& v1, float& v2, float& v3) {
    #pragma unroll
    for (int m = 1; m < 64; m <<= 1) {
        v0 += __shfl_xor(v0, m);
        v1 += __shfl_xor(v1, m);
        v2 += __shfl_xor(v2, m);
        v3 += __shfl_xor(v3, m);
    }
}

// ---------- setup kernels ----------
// h0 = x @ in_w + in_b ; xcur = x ; cnt = 0
__global__ void k_h0(const float* __restrict__ x, const float* __restrict__ in_w,
                     const float* __restrict__ in_b, float* __restrict__ h,
                     float* __restrict__ xcur, unsigned* __restrict__ cnt) {
    int node = (blockIdx.x * blockDim.x + threadIdx.x) >> 6;
    int lane = threadIdx.x & 63;
    if (node >= N_NODES) return;
    float4 xv = ((const float4*)x)[node];
    float hv = in_b[lane] + xv.x * in_w[lane] + xv.y * in_w[64 + lane]
             + xv.z * in_w[128 + lane] + xv.w * in_w[192 + lane];
    h[node * 64 + lane] = hv;
    if (lane == 0) { ((float4*)xcur)[node] = xv; cnt[node] = 0u; }
}

__global__ void k_count(const int* __restrict__ col, unsigned* __restrict__ cnt) {
    int e = blockIdx.x * blockDim.x + threadIdx.x;
    if (e < N_EDGES) atomicAdd(&cnt[col[e]], 1u);
}

// single-block exclusive scan of cnt -> offs ; deg = cnt+1 ; cnt reset to 0 (reused as fill)
__global__ void __launch_bounds__(1024) k_scan(unsigned* __restrict__ cnt,
                                               unsigned* __restrict__ offs,
                                               float* __restrict__ deg) {
    __shared__ unsigned s[1024];
    int tid = threadIdx.x;
    unsigned carry = 0;
    for (int base = 0; base < N_NODES; base += 1024) {
        int i = base + tid;
        unsigned v = (i < N_NODES) ? cnt[i] : 0u;
        s[tid] = v;
        __syncthreads();
        for (int off = 1; off < 1024; off <<= 1) {
            unsigned t_ = (tid >= off) ? s[tid - off] : 0u;
            __syncthreads();
            s[tid] += t_;
            __syncthreads();
        }
        if (i < N_NODES) {
            offs[i] = carry + s[tid] - v;
            deg[i]  = (float)(v + 1u);   // + self loop
            cnt[i]  = 0u;                // reuse as fill counter
        }
        carry += s[1023];
        __syncthreads();
    }
    if (tid == 0) offs[N_NODES] = carry;
}

__global__ void k_scatter(const int* __restrict__ row, const int* __restrict__ col,
                          const unsigned* __restrict__ offs, unsigned* __restrict__ fill,
                          int* __restrict__ srt_row, int* __restrict__ srt_eid) {
    int e = blockIdx.x * blockDim.x + threadIdx.x;
    if (e >= N_EDGES) return;
    int c = col[e];
    unsigned p = offs[c] + atomicAdd(&fill[c], 1u);
    srt_row[p] = row[e];
    srt_eid[p] = e;
}

// ---------- per-layer kernels ----------
// t = h @ rw1[:64] + rb1 ; accum4 = relu(t) @ rw2[:, :4] (self-loop term)
// base4 = rb2[:4] + sb[:4] + h @ sw[:, :4]
__global__ void k1_node(const float* __restrict__ h, const float* __restrict__ rw1,
                        const float* __restrict__ rb1, const float* __restrict__ rw2,
                        const float* __restrict__ rb2, const float* __restrict__ sw,
                        const float* __restrict__ sb, float* __restrict__ t,
                        float* __restrict__ accum4, float* __restrict__ base4) {
    __shared__ float s_rw2[64][4];
    __shared__ float s_sw[64][4];
    int tid = threadIdx.x;
    { int r = tid >> 2, c = tid & 3; s_rw2[r][c] = rw2[r * 64 + c]; s_sw[r][c] = sw[r * 256 + c]; }
    __syncthreads();
    int node = (blockIdx.x * blockDim.x + tid) >> 6;
    int lane = tid & 63;
    if (node >= N_NODES) return;
    float hv = h[node * 64 + lane];
    float acc = rb1[lane];
    #pragma unroll 8
    for (int k = 0; k < 64; k++) acc += __shfl(hv, k) * rw1[k * 64 + lane];
    t[node * 64 + lane] = acc;
    float r = fmaxf(acc, 0.f);
    float v0 = r * s_rw2[lane][0], v1 = r * s_rw2[lane][1];
    float v2 = r * s_rw2[lane][2], v3 = r * s_rw2[lane][3];
    float b0 = hv * s_sw[lane][0], b1 = hv * s_sw[lane][1];
    float b2 = hv * s_sw[lane][2], b3 = hv * s_sw[lane][3];
    bsum4(v0, v1, v2, v3);
    bsum4(b0, b1, b2, b3);
    if (lane == 0) {
        ((float4*)accum4)[node] = make_float4(v0, v1, v2, v3);
        ((float4*)base4)[node]  = make_float4(b0 + rb2[0] + sb[0], b1 + rb2[1] + sb[1],
                                              b2 + rb2[2] + sb[2], b3 + rb2[3] + sb[3]);
    }
}

// per edge: relu(t[src] + ea0*rw1[64] + ea1*rw1[65]) @ rw2[:, :4] -> atomic into accum4[col]
__global__ void k2_edge(const int* __restrict__ row, const int* __restrict__ col,
                        const float* __restrict__ ea, const float* __restrict__ t,
                        const float* __restrict__ rw1, const float* __restrict__ rw2,
                        float* __restrict__ accum4) {
    __shared__ float s_rw2[64][4];
    int tid = threadIdx.x;
    { int r = tid >> 2, c = tid & 3; s_rw2[r][c] = rw2[r * 64 + c]; }
    __syncthreads();
    int lane = tid & 63;
    float wa = rw1[64 * 64 + lane], wb = rw1[65 * 64 + lane];
    float c0 = s_rw2[lane][0], c1 = s_rw2[lane][1], c2 = s_rw2[lane][2], c3 = s_rw2[lane][3];
    int wid = (blockIdx.x * blockDim.x + tid) >> 6;
    int nw  = (gridDim.x * blockDim.x) >> 6;
    for (int e = wid; e < N_EDGES; e += nw) {
        int r = row[e], c = col[e];
        float ea0 = ea[2 * e], ea1 = ea[2 * e + 1];
        float pre = t[r * 64 + lane] + ea0 * wa + ea1 * wb;
        float rr = fmaxf(pre, 0.f);
        float v0 = rr * c0, v1 = rr * c1, v2 = rr * c2, v3 = rr * c3;
        bsum4(v0, v1, v2, v3);
        if (lane < 4) {
            float v = (lane == 0) ? v0 : (lane == 1) ? v1 : (lane == 2) ? v2 : v3;
            atomicAdd(&accum4[c * 4 + lane], v);
        }
    }
}

// x4 = accum4/deg + base4 ; Q/K/V = x4 @ {qw,kw,vw} + bias ; init mx_u/sumexp
__global__ void k3_qkv(const float* __restrict__ accum4, const float* __restrict__ base4,
                       const float* __restrict__ deg, float* __restrict__ x4buf,
                       const float* __restrict__ qw, const float* __restrict__ qb,
                       const float* __restrict__ kw, const float* __restrict__ kb,
                       const float* __restrict__ vw, const float* __restrict__ vb,
                       float* __restrict__ Q, float* __restrict__ K, float* __restrict__ V,
                       unsigned* __restrict__ mx_u, float* __restrict__ sumexp) {
    int tid = threadIdx.x;
    if (blockIdx.x == 0 && tid < 4) { mx_u[tid] = 0u; sumexp[tid] = 0.f; }
    int node = (blockIdx.x * blockDim.x + tid) >> 6;
    int lane = tid & 63;
    if (node >= N_NODES) return;
    float4 a = ((const float4*)accum4)[node];
    float4 b = ((const float4*)base4)[node];
    float idg = 1.f / deg[node];
    float x0 = a.x * idg + b.x, x1 = a.y * idg + b.y;
    float x2 = a.z * idg + b.z, x3 = a.w * idg + b.w;
    if (lane == 0) ((float4*)x4buf)[node] = make_float4(x0, x1, x2, x3);
    float q = qb[lane] + x0 * qw[lane] + x1 * qw[64 + lane] + x2 * qw[128 + lane] + x3 * qw[192 + lane];
    float k = kb[lane] + x0 * kw[lane] + x1 * kw[64 + lane] + x2 * kw[128 + lane] + x3 * kw[192 + lane];
    float v = vb[lane] + x0 * vw[lane] + x1 * vw[64 + lane] + x2 * vw[128 + lane] + x3 * vw[192 + lane];
    Q[node * 64 + lane] = q;
    K[node * 64 + lane] = k;
    V[node * 64 + lane] = v;
}

// scores[e,h] = dot(Q[row],K[col]) per head / 4 ; global max via ordered-uint atomicMax
__global__ void k4_scores(const int* __restrict__ row, const int* __restrict__ col,
                          const float* __restrict__ Q, const float* __restrict__ K,
                          float* __restrict__ scores, unsigned* __restrict__ mx_u) {
    __shared__ unsigned lmax[4];
    int tid = threadIdx.x;
    if (tid < 4) lmax[tid] = 0u;
    __syncthreads();
    int lane = tid & 63;
    int hh = lane >> 4, d = lane & 15;
    float runmax = -1e30f;
    int wid = (blockIdx.x * blockDim.x + tid) >> 6;
    int nw  = (gridDim.x * blockDim.x) >> 6;
    for (int e = wid; e < N_EDGES; e += nw) {
        int r = row[e], c = col[e];
        float p = Q[r * 64 + lane] * K[c * 64 + lane];
        p += __shfl_xor(p, 1); p += __shfl_xor(p, 2);
        p += __shfl_xor(p, 4); p += __shfl_xor(p, 8);
        float sc = p * 0.25f;
        if (d == 0) scores[e * 4 + hh] = sc;
        runmax = fmaxf(runmax, sc);
    }
    if (d == 0) atomicMax(&lmax[hh], f2ord(runmax));
    __syncthreads();
    if (tid < 4) atomicMax(&mx_u[tid], lmax[tid]);
}

// CSR gather: att_raw[c] = sum_{e->c} exp(s-m) * V[row] ; sumexp += partial sums
__global__ void k5_att(const unsigned* __restrict__ offs, const int* __restrict__ srt_row,
                       const int* __restrict__ srt_eid, const float* __restrict__ scores,
                       const unsigned* __restrict__ mx_u, const float* __restrict__ V,
                       float* __restrict__ att_raw, float* __restrict__ sumexp) {
    __shared__ float lsum[4];
    int tid = threadIdx.x;
    if (tid < 4) lsum[tid] = 0.f;
    __syncthreads();
    int lane = tid & 63;
    int hh = lane >> 4, d = lane & 15;
    float mxh = ord2f(mx_u[hh]);
    float sume = 0.f;
    int wid = (blockIdx.x * blockDim.x + tid) >> 6;
    int nw  = (gridDim.x * blockDim.x) >> 6;
    for (int v = wid; v < N_NODES; v += nw) {
        int beg = offs[v], end = offs[v + 1];
        float acc = 0.f;
        for (int p = beg; p < end; p++) {
            int r = srt_row[p];
            int eid = srt_eid[p];
            float ex = __expf(scores[eid * 4 + hh] - mxh);
            acc += ex * V[r * 64 + lane];
            sume += ex;  // identical across the 16 lanes of a head group
        }
        att_raw[v * 64 + lane] = acc;
    }
    if (d == 0) atomicAdd(&lsum[hh], sume);
    __syncthreads();
    if (tid < 4) atomicAdd(&sumexp[tid], lsum[tid]);
}

// finalize: att@ow + ob + x4 -> LN -> + residual*res_w -> xcur ; h = xcur@in_w + in_b
__global__ void k6_fin(const float* __restrict__ att_raw, const float* __restrict__ sumexp,
                       const float* __restrict__ x4buf, const float* __restrict__ ow,
                       const float* __restrict__ ob, const float* __restrict__ g,
                       const float* __restrict__ bb, const float* __restrict__ resw,
                       const float* __restrict__ in_w, const float* __restrict__ in_b,
                       float* __restrict__ xcur, float* __restrict__ h) {
    int tid = threadIdx.x;
    int node = (blockIdx.x * blockDim.x + tid) >> 6;
    int lane = tid & 63;
    if (node >= N_NODES) return;
    float a = att_raw[node * 64 + lane] / sumexp[lane >> 4];
    float4 owv = ((const float4*)ow)[lane];
    float v0 = a * owv.x, v1 = a * owv.y, v2 = a * owv.z, v3 = a * owv.w;
    bsum4(v0, v1, v2, v3);
    float4 x4v = ((const float4*)x4buf)[node];
    float y0 = v0 + ob[0] + x4v.x, y1 = v1 + ob[1] + x4v.y;
    float y2 = v2 + ob[2] + x4v.z, y3 = v3 + ob[3] + x4v.w;
    float mu = 0.25f * (y0 + y1 + y2 + y3);
    float d0 = y0 - mu, d1 = y1 - mu, d2 = y2 - mu, d3 = y3 - mu;
    float var = 0.25f * (d0 * d0 + d1 * d1 + d2 * d2 + d3 * d3);
    float rs = rsqrtf(var + 1e-5f);
    float4 xold = ((const float4*)xcur)[node];
    float rw = resw[0];
    float n0 = d0 * rs * g[0] + bb[0] + xold.x * rw;
    float n1 = d1 * rs * g[1] + bb[1] + xold.y * rw;
    float n2 = d2 * rs * g[2] + bb[2] + xold.z * rw;
    float n3 = d3 * rs * g[3] + bb[3] + xold.w * rw;
    if (lane == 0) ((float4*)xcur)[node] = make_float4(n0, n1, n2, n3);
    float hv = in_b[lane] + n0 * in_w[lane] + n1 * in_w[64 + lane]
             + n2 * in_w[128 + lane] + n3 * in_w[192 + lane];
    h[node * 64 + lane] = hv;
}

// pred = tanh(relu(h@w1+b1)@w2 + b2) * 0.3
__global__ void k_pred(const float* __restrict__ h, const float* __restrict__ w1,
                       const float* __restrict__ b1, const float* __restrict__ w2,
                       const float* __restrict__ b2, float* __restrict__ out) {
    int tid = threadIdx.x;
    int node = (blockIdx.x * blockDim.x + tid) >> 6;
    int lane = tid & 63;
    if (node >= N_NODES) return;
    int j2 = lane & 31;
    float hv = h[node * 64 + lane];
    float m = b1[j2];
    #pragma unroll 8
    for (int k = 0; k < 64; k++) m += __shfl(hv, k) * w1[k * 32 + j2];
    m = fmaxf(m, 0.f);
    float4 w2v = ((const float4*)w2)[j2];
    float v0 = m * w2v.x, v1 = m * w2v.y, v2 = m * w2v.z, v3 = m * w2v.w;
    bsum4(v0, v1, v2, v3);  // each j2 counted twice (both halves) -> *0.5
    float o0 = tanhf(0.5f * v0 + b2[0]) * 0.3f;
    float o1 = tanhf(0.5f * v1 + b2[1]) * 0.3f;
    float o2 = tanhf(0.5f * v2 + b2[2]) * 0.3f;
    float o3 = tanhf(0.5f * v3 + b2[3]) * 0.3f;
    if (lane == 0) ((float4*)out)[node] = make_float4(o0, o1, o2, o3);
}

// ---------- launch ----------
extern "C" void kernel_launch(void* const* d_in, const int* in_sizes, int n_in,
                              void* d_out, int out_size, void* d_ws, size_t ws_size,
                              hipStream_t stream) {
    const float* x        = (const float*)d_in[0];
    const int*   ei       = (const int*)d_in[1];
    const float* ea       = (const float*)d_in[2];
    const float* in_w     = (const float*)d_in[3];
    const float* in_b     = (const float*)d_in[4];
    const float* conv_rw1 = (const float*)d_in[5];
    const float* conv_rb1 = (const float*)d_in[6];
    const float* conv_rw2 = (const float*)d_in[7];
    const float* conv_rb2 = (const float*)d_in[8];
    // d_in[9..12] (imag path) are provably dead: x4 = h4[:, :4] only touches real[:, :4]
    const float* conv_sw  = (const float*)d_in[13];
    const float* conv_sb  = (const float*)d_in[14];
    const float* att_qw   = (const float*)d_in[15];
    const float* att_qb   = (const float*)d_in[16];
    const float* att_kw   = (const float*)d_in[17];
    const float* att_kb   = (const float*)d_in[18];
    const float* att_vw   = (const float*)d_in[19];
    const float* att_vb   = (const float*)d_in[20];
    const float* att_ow   = (const float*)d_in[21];
    const float* att_ob   = (const float*)d_in[22];
    const float* ln_g     = (const float*)d_in[23];
    const float* ln_b     = (const float*)d_in[24];
    const float* out_w1   = (const float*)d_in[25];
    const float* out_b1   = (const float*)d_in[26];
    const float* out_w2   = (const float*)d_in[27];
    const float* out_b2   = (const float*)d_in[28];
    const float* res_w    = (const float*)d_in[29];

    const int* row = ei;
    const int* col = ei + N_EDGES;

    char* ws = (char*)d_ws;
    size_t off = 0;
    auto alloc = [&](size_t bytes) -> void* {
        void* p = ws + off;
        off = (off + bytes + 255) & ~(size_t)255;
        return p;
    };
    float*    deg     = (float*)alloc(N_NODES * 4);
    unsigned* cnt     = (unsigned*)alloc(N_NODES * 4);         // also fill counter
    unsigned* offs    = (unsigned*)alloc((N_NODES + 1) * 4);
    int*      srt_row = (int*)alloc(N_EDGES * 4);
    int*      srt_eid = (int*)alloc(N_EDGES * 4);
    float*    tqa     = (float*)alloc((size_t)N_NODES * 64 * 4); // t / Q / att_raw (lifetimes disjoint)
    float*    Kb      = (float*)alloc((size_t)N_NODES * 64 * 4);
    float*    Vb      = (float*)alloc((size_t)N_NODES * 64 * 4);
    float*    hb      = (float*)alloc((size_t)N_NODES * 64 * 4);
    float*    scores  = (float*)alloc((size_t)N_EDGES * 4 * 4);
    float*    accum4  = (float*)alloc(N_NODES * 4 * 4);
    float*    base4   = (float*)alloc(N_NODES * 4 * 4);
    float*    x4b     = (float*)alloc(N_NODES * 4 * 4);
    float*    xcur    = (float*)alloc(N_NODES * 4 * 4);
    unsigned* mx_u    = (unsigned*)alloc(256);
    float*    sumexp  = (float*)alloc(256);

    dim3 b256(256);
    int nodeBlocks = (N_NODES + 3) / 4;       // wave (64 lanes) per node, 4 per block
    int edgeTB     = (N_EDGES + 255) / 256;   // thread per edge

    k_h0<<<nodeBlocks, b256, 0, stream>>>(x, in_w, in_b, hb, xcur, cnt);
    k_count<<<edgeTB, b256, 0, stream>>>(col, cnt);
    k_scan<<<1, 1024, 0, stream>>>(cnt, offs, deg);
    k_scatter<<<edgeTB, b256, 0, stream>>>(row, col, offs, cnt, srt_row, srt_eid);

    for (int i = 0; i < 4; i++) {
        const float* rw1 = conv_rw1 + i * 66 * 64;
        const float* rb1 = conv_rb1 + i * 64;
        const float* rw2 = conv_rw2 + i * 64 * 64;
        const float* rb2 = conv_rb2 + i * 64;
        const float* swl = conv_sw + i * 64 * 256;
        const float* sbl = conv_sb + i * 256;

        k1_node<<<nodeBlocks, b256, 0, stream>>>(hb, rw1, rb1, rw2, rb2, swl, sbl,
                                                 tqa, accum4, base4);
        k2_edge<<<2048, b256, 0, stream>>>(row, col, ea, tqa, rw1, rw2, accum4);
        k3_qkv<<<nodeBlocks, b256, 0, stream>>>(accum4, base4, deg, x4b,
                                                att_qw + i * 256, att_qb + i * 64,
                                                att_kw + i * 256, att_kb + i * 64,
                                                att_vw + i * 256, att_vb + i * 64,
                                                tqa, Kb, Vb, mx_u, sumexp);
        k4_scores<<<2048, b256, 0, stream>>>(row, col, tqa, Kb, scores, mx_u);
        k5_att<<<2048, b256, 0, stream>>>(offs, srt_row, srt_eid, scores, mx_u, Vb,
                                          tqa, sumexp);
        k6_fin<<<nodeBlocks, b256, 0, stream>>>(tqa, sumexp, x4b,
                                                att_ow + i * 256, att_ob + i * 4,
                                                ln_g + i * 4, ln_b + i * 4, res_w + i,
                                                in_w, in_b, xcur, hb);
    }
    k_pred<<<nodeBlocks, b256, 0, stream>>>(hb, out_w1, out_b1, out_w2, out_b2, (float*)d_out);
}

// Round 2
// 2096.951 us; speedup vs baseline: 1.1628x; 1.1628x over previous
//
#include <hip/hip_runtime.h>
#include <hip/hip_bf16.h>

#define N_NODES 50000
#define N_EDGES 800000

// ---------- helpers ----------
__device__ __forceinline__ unsigned f2ord(float f) {
    unsigned u = __float_as_uint(f);
    return (u & 0x80000000u) ? ~u : (u | 0x80000000u);
}
__device__ __forceinline__ float ord2f(unsigned u) {
    return (u & 0x80000000u) ? __uint_as_float(u & 0x7fffffffu) : __uint_as_float(~u);
}
__device__ __forceinline__ void bsum4(float& v0, float& v1, float& v2, float& v3) {
    #pragma unroll
    for (int m = 1; m < 64; m <<= 1) {
        v0 += __shfl_xor(v0, m);
        v1 += __shfl_xor(v1, m);
        v2 += __shfl_xor(v2, m);
        v3 += __shfl_xor(v3, m);
    }
}

// ---------- setup ----------
// h0 = x @ in_w + in_b ; xcur = x ; zero both count arrays
__global__ void k_h0(const float* __restrict__ x, const float* __restrict__ in_w,
                     const float* __restrict__ in_b, float* __restrict__ h,
                     float* __restrict__ xcur, unsigned* __restrict__ cntC,
                     unsigned* __restrict__ cntR) {
    int node = (blockIdx.x * blockDim.x + threadIdx.x) >> 6;
    int lane = threadIdx.x & 63;
    if (node >= N_NODES) return;
    float4 xv = ((const float4*)x)[node];
    float hv = in_b[lane] + xv.x * in_w[lane] + xv.y * in_w[64 + lane]
             + xv.z * in_w[128 + lane] + xv.w * in_w[192 + lane];
    h[node * 64 + lane] = hv;
    if (lane == 0) { ((float4*)xcur)[node] = xv; cntC[node] = 0u; cntR[node] = 0u; }
}

__global__ void k_count(const int* __restrict__ row, const int* __restrict__ col,
                        unsigned* __restrict__ cntR, unsigned* __restrict__ cntC) {
    int e = blockIdx.x * blockDim.x + threadIdx.x;
    if (e < N_EDGES) {
        atomicAdd(&cntR[row[e]], 1u);
        atomicAdd(&cntC[col[e]], 1u);
    }
}

// dual single-block scan: cntC->offsC (+deg), cntR->offsR ; cnt arrays reset to 0
__global__ void __launch_bounds__(1024) k_scan(unsigned* __restrict__ cntC,
                                               unsigned* __restrict__ offsC,
                                               float* __restrict__ deg,
                                               unsigned* __restrict__ cntR,
                                               unsigned* __restrict__ offsR) {
    __shared__ unsigned s1[1024];
    __shared__ unsigned s2[1024];
    int tid = threadIdx.x;
    unsigned carry1 = 0, carry2 = 0;
    for (int base = 0; base < N_NODES; base += 1024) {
        int i = base + tid;
        unsigned v1 = (i < N_NODES) ? cntC[i] : 0u;
        unsigned v2 = (i < N_NODES) ? cntR[i] : 0u;
        s1[tid] = v1; s2[tid] = v2;
        __syncthreads();
        for (int off = 1; off < 1024; off <<= 1) {
            unsigned t1 = (tid >= off) ? s1[tid - off] : 0u;
            unsigned t2 = (tid >= off) ? s2[tid - off] : 0u;
            __syncthreads();
            s1[tid] += t1; s2[tid] += t2;
            __syncthreads();
        }
        if (i < N_NODES) {
            offsC[i] = carry1 + s1[tid] - v1;
            deg[i]   = (float)(v1 + 1u);      // + self loop
            cntC[i]  = 0u;
            offsR[i] = carry2 + s2[tid] - v2;
            cntR[i]  = 0u;
        }
        carry1 += s1[1023];
        carry2 += s2[1023];
        __syncthreads();
    }
    if (tid == 0) { offsC[N_NODES] = carry1; offsR[N_NODES] = carry2; }
}

// build col-CSR (srt_rowC, srt_dstC) and row-CSR (srt_srcR, srt_colR, ea_srt)
__global__ void k_scatter(const int* __restrict__ row, const int* __restrict__ col,
                          const float* __restrict__ ea,
                          const unsigned* __restrict__ offsC, unsigned* __restrict__ fillC,
                          const unsigned* __restrict__ offsR, unsigned* __restrict__ fillR,
                          int* __restrict__ srt_rowC, int* __restrict__ srt_dstC,
                          int* __restrict__ srt_srcR, int* __restrict__ srt_colR,
                          float2* __restrict__ ea_srt) {
    int e = blockIdx.x * blockDim.x + threadIdx.x;
    if (e >= N_EDGES) return;
    int r = row[e], c = col[e];
    unsigned pC = offsC[c] + atomicAdd(&fillC[c], 1u);
    srt_rowC[pC] = r;
    srt_dstC[pC] = c;
    unsigned pR = offsR[r] + atomicAdd(&fillR[r], 1u);
    srt_srcR[pR] = r;
    srt_colR[pR] = c;
    ea_srt[pR] = make_float2(ea[2 * e], ea[2 * e + 1]);
}

// per-layer per-head score constants: M(16) u(4) v(4) w(1) padded to 32, *0.25 folded
__global__ void k_prep(const float* __restrict__ qw, const float* __restrict__ qb,
                       const float* __restrict__ kw, const float* __restrict__ kb,
                       float* __restrict__ cst) {
    int L = blockIdx.x;
    int m = threadIdx.x;          // 0..63
    int d = m & 15;
    const float* qwl = qw + L * 256; const float* kwl = kw + L * 256;
    const float* qbl = qb + L * 64;  const float* kbl = kb + L * 64;
    float qa[4], ka[4];
    #pragma unroll
    for (int a = 0; a < 4; a++) { qa[a] = qwl[a * 64 + m]; ka[a] = kwl[a * 64 + m]; }
    float qbm = qbl[m], kbm = kbl[m];
    float vals[25];
    int idx = 0;
    #pragma unroll
    for (int a = 0; a < 4; a++)
        #pragma unroll
        for (int b = 0; b < 4; b++) vals[idx++] = qa[a] * ka[b];
    #pragma unroll
    for (int a = 0; a < 4; a++) vals[idx++] = qa[a] * kbm;
    #pragma unroll
    for (int b = 0; b < 4; b++) vals[idx++] = qbm * ka[b];
    vals[24] = qbm * kbm;
    #pragma unroll
    for (int i = 0; i < 25; i++) {
        float v = vals[i];
        v += __shfl_xor(v, 1); v += __shfl_xor(v, 2);
        v += __shfl_xor(v, 4); v += __shfl_xor(v, 8);
        vals[i] = v;
    }
    if (d == 0) {
        float* out = cst + L * 128 + (m >> 4) * 32;
        #pragma unroll
        for (int i = 0; i < 25; i++) out[i] = vals[i] * 0.25f;
    }
}

// ---------- per-layer ----------
// t = h @ rw1[:64] + rb1 ; accum4 = relu(t) @ rw2[:, :4] (self-loop) ; base4
__global__ void k1_node(const float* __restrict__ h, const float* __restrict__ rw1,
                        const float* __restrict__ rb1, const float* __restrict__ rw2,
                        const float* __restrict__ rb2, const float* __restrict__ sw,
                        const float* __restrict__ sb, float* __restrict__ t,
                        float* __restrict__ accum4, float* __restrict__ base4) {
    __shared__ float s_rw2[64][4];
    __shared__ float s_sw[64][4];
    int tid = threadIdx.x;
    { int r = tid >> 2, c = tid & 3; s_rw2[r][c] = rw2[r * 64 + c]; s_sw[r][c] = sw[r * 256 + c]; }
    __syncthreads();
    int node = (blockIdx.x * blockDim.x + tid) >> 6;
    int lane = tid & 63;
    if (node >= N_NODES) return;
    float hv = h[node * 64 + lane];
    float acc = rb1[lane];
    #pragma unroll 8
    for (int k = 0; k < 64; k++) acc += __shfl(hv, k) * rw1[k * 64 + lane];
    t[node * 64 + lane] = acc;
    float r = fmaxf(acc, 0.f);
    float v0 = r * s_rw2[lane][0], v1 = r * s_rw2[lane][1];
    float v2 = r * s_rw2[lane][2], v3 = r * s_rw2[lane][3];
    float b0 = hv * s_sw[lane][0], b1 = hv * s_sw[lane][1];
    float b2 = hv * s_sw[lane][2], b3 = hv * s_sw[lane][3];
    bsum4(v0, v1, v2, v3);
    bsum4(b0, b1, b2, b3);
    if (lane == 0) {
        ((float4*)accum4)[node] = make_float4(v0, v1, v2, v3);
        ((float4*)base4)[node]  = make_float4(b0 + rb2[0] + sb[0], b1 + rb2[1] + sb[1],
                                              b2 + rb2[2] + sb[2], b3 + rb2[3] + sb[3]);
    }
}

// row-CSR sweep: wave walks a contiguous slot chunk, t[src] reloaded only on src change
__global__ void k2_edge_row(const int* __restrict__ srt_srcR, const int* __restrict__ srt_colR,
                            const float2* __restrict__ ea_srt, const float* __restrict__ t,
                            const float* __restrict__ rw1, const float* __restrict__ rw2,
                            float* __restrict__ accum4) {
    __shared__ float s_rw2[64][4];
    int tid = threadIdx.x;
    { int r = tid >> 2, c = tid & 3; s_rw2[r][c] = rw2[r * 64 + c]; }
    __syncthreads();
    int lane = tid & 63;
    float wa = rw1[64 * 64 + lane], wb = rw1[65 * 64 + lane];
    float c0 = s_rw2[lane][0], c1 = s_rw2[lane][1], c2 = s_rw2[lane][2], c3 = s_rw2[lane][3];
    int wid = (blockIdx.x * blockDim.x + tid) >> 6;
    int nw  = (gridDim.x * blockDim.x) >> 6;
    int chunk = (N_EDGES + nw - 1) / nw;
    int start = wid * chunk;
    int end   = min(start + chunk, N_EDGES);
    int cur_r = -1;
    float tv = 0.f;
    for (int p = start; p < end; p++) {
        int r = srt_srcR[p];
        if (r != cur_r) { tv = t[r * 64 + lane]; cur_r = r; }
        int c = srt_colR[p];
        float2 e2 = ea_srt[p];
        float pre = tv + e2.x * wa + e2.y * wb;
        float rr = fmaxf(pre, 0.f);
        float v0 = rr * c0, v1 = rr * c1, v2 = rr * c2, v3 = rr * c3;
        bsum4(v0, v1, v2, v3);
        if (lane < 4) {
            float v = (lane == 0) ? v0 : (lane == 1) ? v1 : (lane == 2) ? v2 : v3;
            atomicAdd(&accum4[c * 4 + lane], v);
        }
    }
}

// x4 = accum4/deg + base4 ; P[node][h][j] = sum_d V[h*16+d]*ow[h*16+d][j] ; init mx/sumexp
__global__ void k3_x4P(const float* __restrict__ accum4, const float* __restrict__ base4,
                       const float* __restrict__ deg, float* __restrict__ x4buf,
                       const float* __restrict__ vw, const float* __restrict__ vb,
                       const float* __restrict__ ow, float* __restrict__ P,
                       unsigned* __restrict__ mx_u, float* __restrict__ sumexp) {
    int tid = threadIdx.x;
    if (blockIdx.x == 0 && tid < 4) { mx_u[tid] = 0u; sumexp[tid] = 0.f; }
    int node = (blockIdx.x * blockDim.x + tid) >> 6;
    int lane = tid & 63;
    if (node >= N_NODES) return;
    float4 a = ((const float4*)accum4)[node];
    float4 b = ((const float4*)base4)[node];
    float idg = 1.f / deg[node];
    float x0 = a.x * idg + b.x, x1 = a.y * idg + b.y;
    float x2 = a.z * idg + b.z, x3 = a.w * idg + b.w;
    if (lane == 0) ((float4*)x4buf)[node] = make_float4(x0, x1, x2, x3);
    float vv = vb[lane] + x0 * vw[lane] + x1 * vw[64 + lane]
             + x2 * vw[128 + lane] + x3 * vw[192 + lane];
    float4 owv = ((const float4*)ow)[lane];
    float p0 = vv * owv.x, p1 = vv * owv.y, p2 = vv * owv.z, p3 = vv * owv.w;
    #pragma unroll
    for (int m = 1; m < 16; m <<= 1) {
        p0 += __shfl_xor(p0, m); p1 += __shfl_xor(p1, m);
        p2 += __shfl_xor(p2, m); p3 += __shfl_xor(p3, m);
    }
    int d = lane & 15;
    if (d < 4) {
        float val = (d == 0) ? p0 : (d == 1) ? p1 : (d == 2) ? p2 : p3;
        P[node * 16 + (lane >> 4) * 4 + d] = val;
    }
}

// col-CSR order, thread per slot: s_e(h) via rank-4 bilinear form; global per-head max
__global__ void k4_scores(const int* __restrict__ srt_rowC, const int* __restrict__ srt_dstC,
                          const float* __restrict__ x4b, const float* __restrict__ cst,
                          float* __restrict__ scores, unsigned* __restrict__ mx_u) {
    __shared__ float sc[128];
    __shared__ unsigned lmax[4];
    int tid = threadIdx.x;
    if (tid < 128) sc[tid] = cst[tid];
    if (tid < 4) lmax[tid] = 0u;
    __syncthreads();
    int p = blockIdx.x * blockDim.x + tid;
    float m0 = -1e30f, m1 = -1e30f, m2 = -1e30f, m3 = -1e30f;
    if (p < N_EDGES) {
        int r = srt_rowC[p], c = srt_dstC[p];
        float4 xr = ((const float4*)x4b)[r];
        float4 xc = ((const float4*)x4b)[c];
        float s[4];
        #pragma unroll
        for (int h = 0; h < 4; h++) {
            const float* C = &sc[h * 32];
            float t0 = xr.x * C[0]  + xr.y * C[4]  + xr.z * C[8]  + xr.w * C[12];
            float t1 = xr.x * C[1]  + xr.y * C[5]  + xr.z * C[9]  + xr.w * C[13];
            float t2 = xr.x * C[2]  + xr.y * C[6]  + xr.z * C[10] + xr.w * C[14];
            float t3 = xr.x * C[3]  + xr.y * C[7]  + xr.z * C[11] + xr.w * C[15];
            float sv = t0 * xc.x + t1 * xc.y + t2 * xc.z + t3 * xc.w
                     + C[16] * xr.x + C[17] * xr.y + C[18] * xr.z + C[19] * xr.w
                     + C[20] * xc.x + C[21] * xc.y + C[22] * xc.z + C[23] * xc.w
                     + C[24];
            s[h] = sv;
        }
        ((float4*)scores)[p] = make_float4(s[0], s[1], s[2], s[3]);
        m0 = s[0]; m1 = s[1]; m2 = s[2]; m3 = s[3];
    }
    #pragma unroll
    for (int m = 1; m < 64; m <<= 1) {
        m0 = fmaxf(m0, __shfl_xor(m0, m));
        m1 = fmaxf(m1, __shfl_xor(m1, m));
        m2 = fmaxf(m2, __shfl_xor(m2, m));
        m3 = fmaxf(m3, __shfl_xor(m3, m));
    }
    if ((tid & 63) == 0) {
        atomicMax(&lmax[0], f2ord(m0));
        atomicMax(&lmax[1], f2ord(m1));
        atomicMax(&lmax[2], f2ord(m2));
        atomicMax(&lmax[3], f2ord(m3));
    }
    __syncthreads();
    if (tid < 4) atomicMax(&mx_u[tid], lmax[tid]);
}

// col-CSR gather: quarter-wave per dst; att16[c][h][j] = sum_e ex * P[r][h][j]
__global__ void k5_att(const unsigned* __restrict__ offsC, const int* __restrict__ srt_rowC,
                       const float* __restrict__ scores, const unsigned* __restrict__ mx_u,
                       const float* __restrict__ P, float* __restrict__ att16,
                       float* __restrict__ sumexp) {
    __shared__ float lsum[4];
    int tid = threadIdx.x;
    if (tid < 4) lsum[tid] = 0.f;
    __syncthreads();
    int lane = tid & 63;
    int sub = lane >> 4, d = lane & 15, h = d >> 2, j = d & 3;
    float mxh = ord2f(mx_u[h]);
    int gid = (blockIdx.x * blockDim.x + tid) >> 6;   // wave id
    int c = gid * 4 + sub;
    float acc = 0.f, sume = 0.f;
    if (c < N_NODES) {
        int beg = offsC[c], end = offsC[c + 1];
        for (int p = beg; p < end; p++) {
            int r = srt_rowC[p];
            float ex = __expf(scores[p * 4 + h] - mxh);
            acc += ex * P[r * 16 + d];
            if (j == 0) sume += ex;
        }
        att16[c * 16 + d] = acc;
    }
    sume += __shfl_xor(sume, 16);
    sume += __shfl_xor(sume, 32);
    if (lane < 16 && j == 0) atomicAdd(&lsum[h], sume);
    __syncthreads();
    if (tid < 4) atomicAdd(&sumexp[tid], lsum[tid]);
}

// finalize: y = sum_h att16/Z_h + ob + x4 -> LN -> + residual -> xcur ; h = xcur@in_w+in_b
__global__ void k6_fin(const float* __restrict__ att16, const float* __restrict__ sumexp,
                       const float* __restrict__ x4buf, const float* __restrict__ ob,
                       const float* __restrict__ g, const float* __restrict__ bb,
                       const float* __restrict__ resw, const float* __restrict__ in_w,
                       const float* __restrict__ in_b, float* __restrict__ xcur,
                       float* __restrict__ h) {
    int tid = threadIdx.x;
    int node = (blockIdx.x * blockDim.x + tid) >> 6;
    int lane = tid & 63;
    if (node >= N_NODES) return;
    float z = sumexp[(lane & 15) >> 2];
    float a = 0.f;
    if (lane < 16) a = att16[node * 16 + lane] / z;
    a += __shfl_xor(a, 4);
    a += __shfl_xor(a, 8);      // lanes 0..3 now hold y_j = sum_h att16[h][j]/Z_h
    float y0 = __shfl(a, 0), y1 = __shfl(a, 1), y2 = __shfl(a, 2), y3 = __shfl(a, 3);
    float4 x4v = ((const float4*)x4buf)[node];
    y0 += ob[0] + x4v.x; y1 += ob[1] + x4v.y;
    y2 += ob[2] + x4v.z; y3 += ob[3] + x4v.w;
    float mu = 0.25f * (y0 + y1 + y2 + y3);
    float d0 = y0 - mu, d1 = y1 - mu, d2 = y2 - mu, d3 = y3 - mu;
    float var = 0.25f * (d0 * d0 + d1 * d1 + d2 * d2 + d3 * d3);
    float rs = rsqrtf(var + 1e-5f);
    float4 xold = ((const float4*)xcur)[node];
    float rw = resw[0];
    float n0 = d0 * rs * g[0] + bb[0] + xold.x * rw;
    float n1 = d1 * rs * g[1] + bb[1] + xold.y * rw;
    float n2 = d2 * rs * g[2] + bb[2] + xold.z * rw;
    float n3 = d3 * rs * g[3] + bb[3] + xold.w * rw;
    if (lane == 0) ((float4*)xcur)[node] = make_float4(n0, n1, n2, n3);
    float hv = in_b[lane] + n0 * in_w[lane] + n1 * in_w[64 + lane]
             + n2 * in_w[128 + lane] + n3 * in_w[192 + lane];
    h[node * 64 + lane] = hv;
}

// pred = tanh(relu(h@w1+b1)@w2 + b2) * 0.3
__global__ void k_pred(const float* __restrict__ h, const float* __restrict__ w1,
                       const float* __restrict__ b1, const float* __restrict__ w2,
                       const float* __restrict__ b2, float* __restrict__ out) {
    int tid = threadIdx.x;
    int node = (blockIdx.x * blockDim.x + tid) >> 6;
    int lane = tid & 63;
    if (node >= N_NODES) return;
    int j2 = lane & 31;
    float hv = h[node * 64 + lane];
    float m = b1[j2];
    #pragma unroll 8
    for (int k = 0; k < 64; k++) m += __shfl(hv, k) * w1[k * 32 + j2];
    m = fmaxf(m, 0.f);
    float4 w2v = ((const float4*)w2)[j2];
    float v0 = m * w2v.x, v1 = m * w2v.y, v2 = m * w2v.z, v3 = m * w2v.w;
    bsum4(v0, v1, v2, v3);  // each j2 counted twice (both halves) -> *0.5
    float o0 = tanhf(0.5f * v0 + b2[0]) * 0.3f;
    float o1 = tanhf(0.5f * v1 + b2[1]) * 0.3f;
    float o2 = tanhf(0.5f * v2 + b2[2]) * 0.3f;
    float o3 = tanhf(0.5f * v3 + b2[3]) * 0.3f;
    if (lane == 0) ((float4*)out)[node] = make_float4(o0, o1, o2, o3);
}

// ---------- launch ----------
extern "C" void kernel_launch(void* const* d_in, const int* in_sizes, int n_in,
                              void* d_out, int out_size, void* d_ws, size_t ws_size,
                              hipStream_t stream) {
    const float* x        = (const float*)d_in[0];
    const int*   ei       = (const int*)d_in[1];
    const float* ea       = (const float*)d_in[2];
    const float* in_w     = (const float*)d_in[3];
    const float* in_b     = (const float*)d_in[4];
    const float* conv_rw1 = (const float*)d_in[5];
    const float* conv_rb1 = (const float*)d_in[6];
    const float* conv_rw2 = (const float*)d_in[7];
    const float* conv_rb2 = (const float*)d_in[8];
    // d_in[9..12] (imag path) dead: x4 = h4[:, :4] only touches real[:, :4]
    const float* conv_sw  = (const float*)d_in[13];
    const float* conv_sb  = (const float*)d_in[14];
    const float* att_qw   = (const float*)d_in[15];
    const float* att_qb   = (const float*)d_in[16];
    const float* att_kw   = (const float*)d_in[17];
    const float* att_kb   = (const float*)d_in[18];
    const float* att_vw   = (const float*)d_in[19];
    const float* att_vb   = (const float*)d_in[20];
    const float* att_ow   = (const float*)d_in[21];
    const float* att_ob   = (const float*)d_in[22];
    const float* ln_g     = (const float*)d_in[23];
    const float* ln_b     = (const float*)d_in[24];
    const float* out_w1   = (const float*)d_in[25];
    const float* out_b1   = (const float*)d_in[26];
    const float* out_w2   = (const float*)d_in[27];
    const float* out_b2   = (const float*)d_in[28];
    const float* res_w    = (const float*)d_in[29];

    const int* row = ei;
    const int* col = ei + N_EDGES;

    char* ws = (char*)d_ws;
    size_t off = 0;
    auto alloc = [&](size_t bytes) -> void* {
        void* p = ws + off;
        off = (off + bytes + 255) & ~(size_t)255;
        return p;
    };
    float*    deg      = (float*)alloc(N_NODES * 4);
    unsigned* cntC     = (unsigned*)alloc(N_NODES * 4);
    unsigned* cntR     = (unsigned*)alloc(N_NODES * 4);
    unsigned* offsC    = (unsigned*)alloc((N_NODES + 1) * 4);
    unsigned* offsR    = (unsigned*)alloc((N_NODES + 1) * 4);
    int*      srt_rowC = (int*)alloc((size_t)N_EDGES * 4);
    int*      srt_dstC = (int*)alloc((size_t)N_EDGES * 4);
    int*      srt_srcR = (int*)alloc((size_t)N_EDGES * 4);
    int*      srt_colR = (int*)alloc((size_t)N_EDGES * 4);
    float2*   ea_srt   = (float2*)alloc((size_t)N_EDGES * 8);
    float*    tbuf     = (float*)alloc((size_t)N_NODES * 64 * 4);
    float*    hb       = (float*)alloc((size_t)N_NODES * 64 * 4);
    float*    Pbuf     = (float*)alloc((size_t)N_NODES * 16 * 4);
    float*    att16    = (float*)alloc((size_t)N_NODES * 16 * 4);
    float*    scores   = (float*)alloc((size_t)N_EDGES * 4 * 4);
    float*    accum4   = (float*)alloc(N_NODES * 4 * 4);
    float*    base4    = (float*)alloc(N_NODES * 4 * 4);
    float*    x4b      = (float*)alloc(N_NODES * 4 * 4);
    float*    xcur     = (float*)alloc(N_NODES * 4 * 4);
    float*    cst      = (float*)alloc(4 * 128 * 4);
    unsigned* mx_u     = (unsigned*)alloc(256);
    float*    sumexp   = (float*)alloc(256);

    dim3 b256(256);
    int nodeBlocks = (N_NODES + 3) / 4;        // wave per node
    int edgeTB     = (N_EDGES + 255) / 256;    // thread per edge
    int dstBlocks  = (N_NODES + 15) / 16;      // quarter-wave per dst

    k_h0<<<nodeBlocks, b256, 0, stream>>>(x, in_w, in_b, hb, xcur, cntC, cntR);
    k_count<<<edgeTB, b256, 0, stream>>>(row, col, cntR, cntC);
    k_scan<<<1, 1024, 0, stream>>>(cntC, offsC, deg, cntR, offsR);
    k_scatter<<<edgeTB, b256, 0, stream>>>(row, col, ea, offsC, cntC, offsR, cntR,
                                           srt_rowC, srt_dstC, srt_srcR, srt_colR, ea_srt);
    k_prep<<<4, 64, 0, stream>>>(att_qw, att_qb, att_kw, att_kb, cst);

    for (int i = 0; i < 4; i++) {
        const float* rw1 = conv_rw1 + i * 66 * 64;
        const float* rb1 = conv_rb1 + i * 64;
        const float* rw2 = conv_rw2 + i * 64 * 64;
        const float* rb2 = conv_rb2 + i * 64;
        const float* swl = conv_sw + i * 64 * 256;
        const float* sbl = conv_sb + i * 256;

        k1_node<<<nodeBlocks, b256, 0, stream>>>(hb, rw1, rb1, rw2, rb2, swl, sbl,
                                                 tbuf, accum4, base4);
        k2_edge_row<<<2048, b256, 0, stream>>>(srt_srcR, srt_colR, ea_srt, tbuf,
                                               rw1, rw2, accum4);
        k3_x4P<<<nodeBlocks, b256, 0, stream>>>(accum4, base4, deg, x4b,
                                                att_vw + i * 256, att_vb + i * 64,
                                                att_ow + i * 256, Pbuf, mx_u, sumexp);
        k4_scores<<<edgeTB, b256, 0, stream>>>(srt_rowC, srt_dstC, x4b, cst + i * 128,
                                               scores, mx_u);
        k5_att<<<dstBlocks, b256, 0, stream>>>(offsC, srt_rowC, scores, mx_u, Pbuf,
                                               att16, sumexp);
        k6_fin<<<nodeBlocks, b256, 0, stream>>>(att16, sumexp, x4b,
                                                att_ob + i * 4, ln_g + i * 4,
                                                ln_b + i * 4, res_w + i,
                                                in_w, in_b, xcur, hb);
    }
    k_pred<<<nodeBlocks, b256, 0, stream>>>(hb, out_w1, out_b1, out_w2, out_b2, (float*)d_out);
}

// Round 3
// 1846.630 us; speedup vs baseline: 1.3205x; 1.1356x over previous
//
#include <hip/hip_runtime.h>
#include <hip/hip_bf16.h>

#define N_NODES 50000
#define N_EDGES 800000

// ---------- helpers ----------
__device__ __forceinline__ unsigned f2ord(float f) {
    unsigned u = __float_as_uint(f);
    return (u & 0x80000000u) ? ~u : (u | 0x80000000u);
}
__device__ __forceinline__ float ord2f(unsigned u) {
    return (u & 0x80000000u) ? __uint_as_float(u & 0x7fffffffu) : __uint_as_float(~u);
}
__device__ __forceinline__ void bsum4(float& v0, float& v1, float& v2, float& v3) {
    #pragma unroll
    for (int m = 1; m < 64; m <<= 1) {
        v0 += __shfl_xor(v0, m);
        v1 += __shfl_xor(v1, m);
        v2 += __shfl_xor(v2, m);
        v3 += __shfl_xor(v3, m);
    }
}

// ---------- setup ----------
__global__ void k_h0(const float* __restrict__ x, const float* __restrict__ in_w,
                     const float* __restrict__ in_b, float* __restrict__ h,
                     float* __restrict__ xcur, unsigned* __restrict__ cntC,
                     unsigned* __restrict__ cntR) {
    int node = (blockIdx.x * blockDim.x + threadIdx.x) >> 6;
    int lane = threadIdx.x & 63;
    if (node >= N_NODES) return;
    float4 xv = ((const float4*)x)[node];
    float hv = in_b[lane] + xv.x * in_w[lane] + xv.y * in_w[64 + lane]
             + xv.z * in_w[128 + lane] + xv.w * in_w[192 + lane];
    h[node * 64 + lane] = hv;
    if (lane == 0) { ((float4*)xcur)[node] = xv; cntC[node] = 0u; cntR[node] = 0u; }
}

__global__ void k_count(const int* __restrict__ row, const int* __restrict__ col,
                        unsigned* __restrict__ cntR, unsigned* __restrict__ cntC) {
    int e = blockIdx.x * blockDim.x + threadIdx.x;
    if (e < N_EDGES) {
        atomicAdd(&cntR[row[e]], 1u);
        atomicAdd(&cntC[col[e]], 1u);
    }
}

__global__ void __launch_bounds__(1024) k_scan(unsigned* __restrict__ cntC,
                                               unsigned* __restrict__ offsC,
                                               float* __restrict__ deg,
                                               unsigned* __restrict__ cntR,
                                               unsigned* __restrict__ offsR) {
    __shared__ unsigned s1[1024];
    __shared__ unsigned s2[1024];
    int tid = threadIdx.x;
    unsigned carry1 = 0, carry2 = 0;
    for (int base = 0; base < N_NODES; base += 1024) {
        int i = base + tid;
        unsigned v1 = (i < N_NODES) ? cntC[i] : 0u;
        unsigned v2 = (i < N_NODES) ? cntR[i] : 0u;
        s1[tid] = v1; s2[tid] = v2;
        __syncthreads();
        for (int off = 1; off < 1024; off <<= 1) {
            unsigned t1 = (tid >= off) ? s1[tid - off] : 0u;
            unsigned t2 = (tid >= off) ? s2[tid - off] : 0u;
            __syncthreads();
            s1[tid] += t1; s2[tid] += t2;
            __syncthreads();
        }
        if (i < N_NODES) {
            offsC[i] = carry1 + s1[tid] - v1;
            deg[i]   = (float)(v1 + 1u);
            cntC[i]  = 0u;
            offsR[i] = carry2 + s2[tid] - v2;
            cntR[i]  = 0u;
        }
        carry1 += s1[1023];
        carry2 += s2[1023];
        __syncthreads();
    }
    if (tid == 0) { offsC[N_NODES] = carry1; offsR[N_NODES] = carry2; }
}

__global__ void k_scatter(const int* __restrict__ row, const int* __restrict__ col,
                          const float* __restrict__ ea,
                          const unsigned* __restrict__ offsC, unsigned* __restrict__ fillC,
                          const unsigned* __restrict__ offsR, unsigned* __restrict__ fillR,
                          int* __restrict__ srt_rowC, int* __restrict__ srt_dstC,
                          int* __restrict__ srt_srcR, int* __restrict__ srt_colR,
                          float2* __restrict__ ea_srt) {
    int e = blockIdx.x * blockDim.x + threadIdx.x;
    if (e >= N_EDGES) return;
    int r = row[e], c = col[e];
    unsigned pC = offsC[c] + atomicAdd(&fillC[c], 1u);
    srt_rowC[pC] = r;
    srt_dstC[pC] = c;
    unsigned pR = offsR[r] + atomicAdd(&fillR[r], 1u);
    srt_srcR[pR] = r;
    srt_colR[pR] = c;
    ea_srt[pR] = make_float2(ea[2 * e], ea[2 * e + 1]);
}

// per-layer per-head score constants: M(16) u(4) v(4) w(1) padded to 32, *0.25 folded
__global__ void k_prep(const float* __restrict__ qw, const float* __restrict__ qb,
                       const float* __restrict__ kw, const float* __restrict__ kb,
                       float* __restrict__ cst) {
    int L = blockIdx.x;
    int m = threadIdx.x;
    int d = m & 15;
    const float* qwl = qw + L * 256; const float* kwl = kw + L * 256;
    const float* qbl = qb + L * 64;  const float* kbl = kb + L * 64;
    float qa[4], ka[4];
    #pragma unroll
    for (int a = 0; a < 4; a++) { qa[a] = qwl[a * 64 + m]; ka[a] = kwl[a * 64 + m]; }
    float qbm = qbl[m], kbm = kbl[m];
    float vals[25];
    int idx = 0;
    #pragma unroll
    for (int a = 0; a < 4; a++)
        #pragma unroll
        for (int b = 0; b < 4; b++) vals[idx++] = qa[a] * ka[b];
    #pragma unroll
    for (int a = 0; a < 4; a++) vals[idx++] = qa[a] * kbm;
    #pragma unroll
    for (int b = 0; b < 4; b++) vals[idx++] = qbm * ka[b];
    vals[24] = qbm * kbm;
    #pragma unroll
    for (int i = 0; i < 25; i++) {
        float v = vals[i];
        v += __shfl_xor(v, 1); v += __shfl_xor(v, 2);
        v += __shfl_xor(v, 4); v += __shfl_xor(v, 8);
        vals[i] = v;
    }
    if (d == 0) {
        float* out = cst + L * 128 + (m >> 4) * 32;
        #pragma unroll
        for (int i = 0; i < 25; i++) out[i] = vals[i] * 0.25f;
    }
}

// ---------- per-layer ----------
// 4 nodes per wave: t = h @ rw1[:64] + rb1 ; accum4 self-loop term ; base4
__global__ void k1_node(const float* __restrict__ h, const float* __restrict__ rw1,
                        const float* __restrict__ rb1, const float* __restrict__ rw2,
                        const float* __restrict__ rb2, const float* __restrict__ sw,
                        const float* __restrict__ sb, float* __restrict__ t,
                        float* __restrict__ accum4, float* __restrict__ base4) {
    __shared__ float s_rw2[64][4];
    __shared__ float s_sw[64][4];
    int tid = threadIdx.x;
    { int r = tid >> 2, c = tid & 3; s_rw2[r][c] = rw2[r * 64 + c]; s_sw[r][c] = sw[r * 256 + c]; }
    __syncthreads();
    int wid = (blockIdx.x * blockDim.x + tid) >> 6;
    int lane = tid & 63;
    int n0 = wid * 4;
    if (n0 >= N_NODES) return;
    float hv[4], acc[4];
    #pragma unroll
    for (int i = 0; i < 4; i++) {
        int n = n0 + i;
        hv[i]  = (n < N_NODES) ? h[n * 64 + lane] : 0.f;
        acc[i] = rb1[lane];
    }
    for (int k = 0; k < 64; k++) {
        float w = rw1[k * 64 + lane];
        #pragma unroll
        for (int i = 0; i < 4; i++) acc[i] += __shfl(hv[i], k) * w;
    }
    float rb2_0 = rb2[0] + sb[0], rb2_1 = rb2[1] + sb[1];
    float rb2_2 = rb2[2] + sb[2], rb2_3 = rb2[3] + sb[3];
    #pragma unroll
    for (int i = 0; i < 4; i++) {
        int n = n0 + i;
        if (n >= N_NODES) break;
        t[n * 64 + lane] = acc[i];
        float r = fmaxf(acc[i], 0.f);
        float v0 = r * s_rw2[lane][0], v1 = r * s_rw2[lane][1];
        float v2 = r * s_rw2[lane][2], v3 = r * s_rw2[lane][3];
        float b0 = hv[i] * s_sw[lane][0], b1 = hv[i] * s_sw[lane][1];
        float b2 = hv[i] * s_sw[lane][2], b3 = hv[i] * s_sw[lane][3];
        bsum4(v0, v1, v2, v3);
        bsum4(b0, b1, b2, b3);
        if (lane == 0) {
            ((float4*)accum4)[n] = make_float4(v0, v1, v2, v3);
            ((float4*)base4)[n]  = make_float4(b0 + rb2_0, b1 + rb2_1, b2 + rb2_2, b3 + rb2_3);
        }
    }
}

// one edge per LANE: walk 64 channels in registers; weights via uniform scalar loads;
// row-CSR order keeps t[src] rows L1-resident (few distinct rows per wave)
__global__ void k2_edge_lane(const int* __restrict__ srt_srcR, const int* __restrict__ srt_colR,
                             const float2* __restrict__ ea_srt, const float* __restrict__ t,
                             const float* __restrict__ rw1, const float* __restrict__ rw2,
                             float* __restrict__ accum4) {
    int e = blockIdx.x * blockDim.x + threadIdx.x;
    if (e >= N_EDGES) return;
    int src = srt_srcR[e];
    int c   = srt_colR[e];
    float2 e2 = ea_srt[e];
    const float4* t4 = (const float4*)(t + (size_t)src * 64);
    float v0 = 0.f, v1 = 0.f, v2 = 0.f, v3 = 0.f;
    #pragma unroll
    for (int kc = 0; kc < 16; kc++) {
        float4 tv = t4[kc];
        #pragma unroll
        for (int j = 0; j < 4; j++) {
            int k = kc * 4 + j;
            float tk = (j == 0) ? tv.x : (j == 1) ? tv.y : (j == 2) ? tv.z : tv.w;
            float pre = tk + e2.x * rw1[64 * 64 + k] + e2.y * rw1[65 * 64 + k];
            float rr = fmaxf(pre, 0.f);
            v0 += rr * rw2[k * 64 + 0];
            v1 += rr * rw2[k * 64 + 1];
            v2 += rr * rw2[k * 64 + 2];
            v3 += rr * rw2[k * 64 + 3];
        }
    }
    atomicAdd(&accum4[c * 4 + 0], v0);
    atomicAdd(&accum4[c * 4 + 1], v1);
    atomicAdd(&accum4[c * 4 + 2], v2);
    atomicAdd(&accum4[c * 4 + 3], v3);
}

// x4 = accum4/deg + base4 ; P[node][h][j] = sum_d V[h*16+d]*ow[h*16+d][j]
__global__ void k3_x4P(const float* __restrict__ accum4, const float* __restrict__ base4,
                       const float* __restrict__ deg, float* __restrict__ x4buf,
                       const float* __restrict__ vw, const float* __restrict__ vb,
                       const float* __restrict__ ow, float* __restrict__ P,
                       unsigned* __restrict__ mx_u, float* __restrict__ sumexp) {
    int tid = threadIdx.x;
    if (blockIdx.x == 0 && tid < 4) { mx_u[tid] = 0u; sumexp[tid] = 0.f; }
    int node = (blockIdx.x * blockDim.x + tid) >> 6;
    int lane = tid & 63;
    if (node >= N_NODES) return;
    float4 a = ((const float4*)accum4)[node];
    float4 b = ((const float4*)base4)[node];
    float idg = 1.f / deg[node];
    float x0 = a.x * idg + b.x, x1 = a.y * idg + b.y;
    float x2 = a.z * idg + b.z, x3 = a.w * idg + b.w;
    if (lane == 0) ((float4*)x4buf)[node] = make_float4(x0, x1, x2, x3);
    float vv = vb[lane] + x0 * vw[lane] + x1 * vw[64 + lane]
             + x2 * vw[128 + lane] + x3 * vw[192 + lane];
    float4 owv = ((const float4*)ow)[lane];
    float p0 = vv * owv.x, p1 = vv * owv.y, p2 = vv * owv.z, p3 = vv * owv.w;
    #pragma unroll
    for (int m = 1; m < 16; m <<= 1) {
        p0 += __shfl_xor(p0, m); p1 += __shfl_xor(p1, m);
        p2 += __shfl_xor(p2, m); p3 += __shfl_xor(p3, m);
    }
    int d = lane & 15;
    if (d < 4) {
        float val = (d == 0) ? p0 : (d == 1) ? p1 : (d == 2) ? p2 : p3;
        P[node * 16 + (lane >> 4) * 4 + d] = val;
    }
}

// thread per slot: s_e(h) via rank-4 bilinear form; global per-head max
__global__ void k4_scores(const int* __restrict__ srt_rowC, const int* __restrict__ srt_dstC,
                          const float* __restrict__ x4b, const float* __restrict__ cst,
                          float* __restrict__ scores, unsigned* __restrict__ mx_u) {
    __shared__ float sc[128];
    __shared__ unsigned lmax[4];
    int tid = threadIdx.x;
    if (tid < 128) sc[tid] = cst[tid];
    if (tid < 4) lmax[tid] = 0u;
    __syncthreads();
    int p = blockIdx.x * blockDim.x + tid;
    float m0 = -1e30f, m1 = -1e30f, m2 = -1e30f, m3 = -1e30f;
    if (p < N_EDGES) {
        int r = srt_rowC[p], c = srt_dstC[p];
        float4 xr = ((const float4*)x4b)[r];
        float4 xc = ((const float4*)x4b)[c];
        float s[4];
        #pragma unroll
        for (int h = 0; h < 4; h++) {
            const float* C = &sc[h * 32];
            float t0 = xr.x * C[0]  + xr.y * C[4]  + xr.z * C[8]  + xr.w * C[12];
            float t1 = xr.x * C[1]  + xr.y * C[5]  + xr.z * C[9]  + xr.w * C[13];
            float t2 = xr.x * C[2]  + xr.y * C[6]  + xr.z * C[10] + xr.w * C[14];
            float t3 = xr.x * C[3]  + xr.y * C[7]  + xr.z * C[11] + xr.w * C[15];
            float sv = t0 * xc.x + t1 * xc.y + t2 * xc.z + t3 * xc.w
                     + C[16] * xr.x + C[17] * xr.y + C[18] * xr.z + C[19] * xr.w
                     + C[20] * xc.x + C[21] * xc.y + C[22] * xc.z + C[23] * xc.w
                     + C[24];
            s[h] = sv;
        }
        ((float4*)scores)[p] = make_float4(s[0], s[1], s[2], s[3]);
        m0 = s[0]; m1 = s[1]; m2 = s[2]; m3 = s[3];
    }
    #pragma unroll
    for (int m = 1; m < 64; m <<= 1) {
        m0 = fmaxf(m0, __shfl_xor(m0, m));
        m1 = fmaxf(m1, __shfl_xor(m1, m));
        m2 = fmaxf(m2, __shfl_xor(m2, m));
        m3 = fmaxf(m3, __shfl_xor(m3, m));
    }
    if ((tid & 63) == 0) {
        atomicMax(&lmax[0], f2ord(m0));
        atomicMax(&lmax[1], f2ord(m1));
        atomicMax(&lmax[2], f2ord(m2));
        atomicMax(&lmax[3], f2ord(m3));
    }
    __syncthreads();
    if (tid < 4) atomicMax(&mx_u[tid], lmax[tid]);
}

// col-CSR gather: quarter-wave per dst; att16[c][h][j] = sum_e ex * P[r][h][j]
__global__ void k5_att(const unsigned* __restrict__ offsC, const int* __restrict__ srt_rowC,
                       const float* __restrict__ scores, const unsigned* __restrict__ mx_u,
                       const float* __restrict__ P, float* __restrict__ att16,
                       float* __restrict__ sumexp) {
    __shared__ float lsum[4];
    int tid = threadIdx.x;
    if (tid < 4) lsum[tid] = 0.f;
    __syncthreads();
    int lane = tid & 63;
    int sub = lane >> 4, d = lane & 15, h = d >> 2, j = d & 3;
    float mxh = ord2f(mx_u[h]);
    int gid = (blockIdx.x * blockDim.x + tid) >> 6;
    int c = gid * 4 + sub;
    float acc = 0.f, sume = 0.f;
    if (c < N_NODES) {
        int beg = offsC[c], end = offsC[c + 1];
        for (int p = beg; p < end; p++) {
            int r = srt_rowC[p];
            float ex = __expf(scores[p * 4 + h] - mxh);
            acc += ex * P[r * 16 + d];
            if (j == 0) sume += ex;
        }
        att16[c * 16 + d] = acc;
    }
    sume += __shfl_xor(sume, 16);
    sume += __shfl_xor(sume, 32);
    if (lane < 16 && j == 0) atomicAdd(&lsum[h], sume);
    __syncthreads();
    if (tid < 4) atomicAdd(&sumexp[tid], lsum[tid]);
}

// finalize: y = sum_h att16/Z_h + ob + x4 -> LN -> + residual -> xcur ; h = xcur@in_w+in_b
__global__ void k6_fin(const float* __restrict__ att16, const float* __restrict__ sumexp,
                       const float* __restrict__ x4buf, const float* __restrict__ ob,
                       const float* __restrict__ g, const float* __restrict__ bb,
                       const float* __restrict__ resw, const float* __restrict__ in_w,
                       const float* __restrict__ in_b, float* __restrict__ xcur,
                       float* __restrict__ h) {
    int tid = threadIdx.x;
    int node = (blockIdx.x * blockDim.x + tid) >> 6;
    int lane = tid & 63;
    if (node >= N_NODES) return;
    float z = sumexp[(lane & 15) >> 2];
    float a = 0.f;
    if (lane < 16) a = att16[node * 16 + lane] / z;
    a += __shfl_xor(a, 4);
    a += __shfl_xor(a, 8);
    float y0 = __shfl(a, 0), y1 = __shfl(a, 1), y2 = __shfl(a, 2), y3 = __shfl(a, 3);
    float4 x4v = ((const float4*)x4buf)[node];
    y0 += ob[0] + x4v.x; y1 += ob[1] + x4v.y;
    y2 += ob[2] + x4v.z; y3 += ob[3] + x4v.w;
    float mu = 0.25f * (y0 + y1 + y2 + y3);
    float d0 = y0 - mu, d1 = y1 - mu, d2 = y2 - mu, d3 = y3 - mu;
    float var = 0.25f * (d0 * d0 + d1 * d1 + d2 * d2 + d3 * d3);
    float rs = rsqrtf(var + 1e-5f);
    float4 xold = ((const float4*)xcur)[node];
    float rw = resw[0];
    float n0 = d0 * rs * g[0] + bb[0] + xold.x * rw;
    float n1 = d1 * rs * g[1] + bb[1] + xold.y * rw;
    float n2 = d2 * rs * g[2] + bb[2] + xold.z * rw;
    float n3 = d3 * rs * g[3] + bb[3] + xold.w * rw;
    if (lane == 0) ((float4*)xcur)[node] = make_float4(n0, n1, n2, n3);
    float hv = in_b[lane] + n0 * in_w[lane] + n1 * in_w[64 + lane]
             + n2 * in_w[128 + lane] + n3 * in_w[192 + lane];
    h[node * 64 + lane] = hv;
}

// pred = tanh(relu(h@w1+b1)@w2 + b2) * 0.3
__global__ void k_pred(const float* __restrict__ h, const float* __restrict__ w1,
                       const float* __restrict__ b1, const float* __restrict__ w2,
                       const float* __restrict__ b2, float* __restrict__ out) {
    int tid = threadIdx.x;
    int node = (blockIdx.x * blockDim.x + tid) >> 6;
    int lane = tid & 63;
    if (node >= N_NODES) return;
    int j2 = lane & 31;
    float hv = h[node * 64 + lane];
    float m = b1[j2];
    #pragma unroll 8
    for (int k = 0; k < 64; k++) m += __shfl(hv, k) * w1[k * 32 + j2];
    m = fmaxf(m, 0.f);
    float4 w2v = ((const float4*)w2)[j2];
    float v0 = m * w2v.x, v1 = m * w2v.y, v2 = m * w2v.z, v3 = m * w2v.w;
    bsum4(v0, v1, v2, v3);
    float o0 = tanhf(0.5f * v0 + b2[0]) * 0.3f;
    float o1 = tanhf(0.5f * v1 + b2[1]) * 0.3f;
    float o2 = tanhf(0.5f * v2 + b2[2]) * 0.3f;
    float o3 = tanhf(0.5f * v3 + b2[3]) * 0.3f;
    if (lane == 0) ((float4*)out)[node] = make_float4(o0, o1, o2, o3);
}

// ---------- launch ----------
extern "C" void kernel_launch(void* const* d_in, const int* in_sizes, int n_in,
                              void* d_out, int out_size, void* d_ws, size_t ws_size,
                              hipStream_t stream) {
    const float* x        = (const float*)d_in[0];
    const int*   ei       = (const int*)d_in[1];
    const float* ea       = (const float*)d_in[2];
    const float* in_w     = (const float*)d_in[3];
    const float* in_b     = (const float*)d_in[4];
    const float* conv_rw1 = (const float*)d_in[5];
    const float* conv_rb1 = (const float*)d_in[6];
    const float* conv_rw2 = (const float*)d_in[7];
    const float* conv_rb2 = (const float*)d_in[8];
    // d_in[9..12] (imag path) dead: x4 = h4[:, :4] only touches real[:, :4]
    const float* conv_sw  = (const float*)d_in[13];
    const float* conv_sb  = (const float*)d_in[14];
    const float* att_qw   = (const float*)d_in[15];
    const float* att_qb   = (const float*)d_in[16];
    const float* att_kw   = (const float*)d_in[17];
    const float* att_kb   = (const float*)d_in[18];
    const float* att_vw   = (const float*)d_in[19];
    const float* att_vb   = (const float*)d_in[20];
    const float* att_ow   = (const float*)d_in[21];
    const float* att_ob   = (const float*)d_in[22];
    const float* ln_g     = (const float*)d_in[23];
    const float* ln_b     = (const float*)d_in[24];
    const float* out_w1   = (const float*)d_in[25];
    const float* out_b1   = (const float*)d_in[26];
    const float* out_w2   = (const float*)d_in[27];
    const float* out_b2   = (const float*)d_in[28];
    const float* res_w    = (const float*)d_in[29];

    const int* row = ei;
    const int* col = ei + N_EDGES;

    char* ws = (char*)d_ws;
    size_t off = 0;
    auto alloc = [&](size_t bytes) -> void* {
        void* p = ws + off;
        off = (off + bytes + 255) & ~(size_t)255;
        return p;
    };
    float*    deg      = (float*)alloc(N_NODES * 4);
    unsigned* cntC     = (unsigned*)alloc(N_NODES * 4);
    unsigned* cntR     = (unsigned*)alloc(N_NODES * 4);
    unsigned* offsC    = (unsigned*)alloc((N_NODES + 1) * 4);
    unsigned* offsR    = (unsigned*)alloc((N_NODES + 1) * 4);
    int*      srt_rowC = (int*)alloc((size_t)N_EDGES * 4);
    int*      srt_dstC = (int*)alloc((size_t)N_EDGES * 4);
    int*      srt_srcR = (int*)alloc((size_t)N_EDGES * 4);
    int*      srt_colR = (int*)alloc((size_t)N_EDGES * 4);
    float2*   ea_srt   = (float2*)alloc((size_t)N_EDGES * 8);
    float*    tbuf     = (float*)alloc((size_t)N_NODES * 64 * 4);
    float*    hb       = (float*)alloc((size_t)N_NODES * 64 * 4);
    float*    Pbuf     = (float*)alloc((size_t)N_NODES * 16 * 4);
    float*    att16    = (float*)alloc((size_t)N_NODES * 16 * 4);
    float*    scores   = (float*)alloc((size_t)N_EDGES * 4 * 4);
    float*    accum4   = (float*)alloc(N_NODES * 4 * 4);
    float*    base4    = (float*)alloc(N_NODES * 4 * 4);
    float*    x4b      = (float*)alloc(N_NODES * 4 * 4);
    float*    xcur     = (float*)alloc(N_NODES * 4 * 4);
    float*    cst      = (float*)alloc(4 * 128 * 4);
    unsigned* mx_u     = (unsigned*)alloc(256);
    float*    sumexp   = (float*)alloc(256);

    dim3 b256(256);
    int nodeBlocks  = (N_NODES + 3) / 4;        // wave per node
    int nodeBlocks4 = (N_NODES + 15) / 16;      // wave per 4 nodes
    int edgeTB      = (N_EDGES + 255) / 256;    // thread per edge
    int dstBlocks   = (N_NODES + 15) / 16;      // quarter-wave per dst

    k_h0<<<nodeBlocks, b256, 0, stream>>>(x, in_w, in_b, hb, xcur, cntC, cntR);
    k_count<<<edgeTB, b256, 0, stream>>>(row, col, cntR, cntC);
    k_scan<<<1, 1024, 0, stream>>>(cntC, offsC, deg, cntR, offsR);
    k_scatter<<<edgeTB, b256, 0, stream>>>(row, col, ea, offsC, cntC, offsR, cntR,
                                           srt_rowC, srt_dstC, srt_srcR, srt_colR, ea_srt);
    k_prep<<<4, 64, 0, stream>>>(att_qw, att_qb, att_kw, att_kb, cst);

    for (int i = 0; i < 4; i++) {
        const float* rw1 = conv_rw1 + i * 66 * 64;
        const float* rb1 = conv_rb1 + i * 64;
        const float* rw2 = conv_rw2 + i * 64 * 64;
        const float* rb2 = conv_rb2 + i * 64;
        const float* swl = conv_sw + i * 64 * 256;
        const float* sbl = conv_sb + i * 256;

        k1_node<<<nodeBlocks4, b256, 0, stream>>>(hb, rw1, rb1, rw2, rb2, swl, sbl,
                                                  tbuf, accum4, base4);
        k2_edge_lane<<<edgeTB, b256, 0, stream>>>(srt_srcR, srt_colR, ea_srt, tbuf,
                                                  rw1, rw2, accum4);
        k3_x4P<<<nodeBlocks, b256, 0, stream>>>(accum4, base4, deg, x4b,
                                                att_vw + i * 256, att_vb + i * 64,
                                                att_ow + i * 256, Pbuf, mx_u, sumexp);
        k4_scores<<<edgeTB, b256, 0, stream>>>(srt_rowC, srt_dstC, x4b, cst + i * 128,
                                               scores, mx_u);
        k5_att<<<dstBlocks, b256, 0, stream>>>(offsC, srt_rowC, scores, mx_u, Pbuf,
                                               att16, sumexp);
        k6_fin<<<nodeBlocks, b256, 0, stream>>>(att16, sumexp, x4b,
                                                att_ob + i * 4, ln_g + i * 4,
                                                ln_b + i * 4, res_w + i,
                                                in_w, in_b, xcur, hb);
    }
    k_pred<<<nodeBlocks, b256, 0, stream>>>(hb, out_w1, out_b1, out_w2, out_b2, (float*)d_out);
}

// Round 4
// 1283.383 us; speedup vs baseline: 1.9000x; 1.4389x over previous
//
#include <hip/hip_runtime.h>
#include <hip/hip_bf16.h>

#define N_NODES 50000
#define N_EDGES 800000

// ---------- helpers ----------
__device__ __forceinline__ unsigned f2ord(float f) {
    unsigned u = __float_as_uint(f);
    return (u & 0x80000000u) ? ~u : (u | 0x80000000u);
}
__device__ __forceinline__ float ord2f(unsigned u) {
    return (u & 0x80000000u) ? __uint_as_float(u & 0x7fffffffu) : __uint_as_float(~u);
}
__device__ __forceinline__ void bsum4(float& v0, float& v1, float& v2, float& v3) {
    #pragma unroll
    for (int m = 1; m < 64; m <<= 1) {
        v0 += __shfl_xor(v0, m);
        v1 += __shfl_xor(v1, m);
        v2 += __shfl_xor(v2, m);
        v3 += __shfl_xor(v3, m);
    }
}

// ---------- setup ----------
__global__ void k_h0(const float* __restrict__ x, const float* __restrict__ in_w,
                     const float* __restrict__ in_b, float* __restrict__ h,
                     float* __restrict__ xcur, unsigned* __restrict__ cntC,
                     unsigned* __restrict__ cntR) {
    int node = (blockIdx.x * blockDim.x + threadIdx.x) >> 6;
    int lane = threadIdx.x & 63;
    if (node >= N_NODES) return;
    float4 xv = ((const float4*)x)[node];
    float hv = in_b[lane] + xv.x * in_w[lane] + xv.y * in_w[64 + lane]
             + xv.z * in_w[128 + lane] + xv.w * in_w[192 + lane];
    h[node * 64 + lane] = hv;
    if (lane == 0) { ((float4*)xcur)[node] = xv; cntC[node] = 0u; cntR[node] = 0u; }
}

__global__ void k_count(const int* __restrict__ row, const int* __restrict__ col,
                        unsigned* __restrict__ cntR, unsigned* __restrict__ cntC) {
    int e = blockIdx.x * blockDim.x + threadIdx.x;
    if (e < N_EDGES) {
        atomicAdd(&cntR[row[e]], 1u);
        atomicAdd(&cntC[col[e]], 1u);
    }
}

__global__ void __launch_bounds__(1024) k_scan(unsigned* __restrict__ cntC,
                                               unsigned* __restrict__ offsC,
                                               float* __restrict__ deg,
                                               unsigned* __restrict__ cntR,
                                               unsigned* __restrict__ offsR) {
    __shared__ unsigned s1[1024];
    __shared__ unsigned s2[1024];
    int tid = threadIdx.x;
    unsigned carry1 = 0, carry2 = 0;
    for (int base = 0; base < N_NODES; base += 1024) {
        int i = base + tid;
        unsigned v1 = (i < N_NODES) ? cntC[i] : 0u;
        unsigned v2 = (i < N_NODES) ? cntR[i] : 0u;
        s1[tid] = v1; s2[tid] = v2;
        __syncthreads();
        for (int off = 1; off < 1024; off <<= 1) {
            unsigned t1 = (tid >= off) ? s1[tid - off] : 0u;
            unsigned t2 = (tid >= off) ? s2[tid - off] : 0u;
            __syncthreads();
            s1[tid] += t1; s2[tid] += t2;
            __syncthreads();
        }
        if (i < N_NODES) {
            offsC[i] = carry1 + s1[tid] - v1;
            deg[i]   = (float)(v1 + 1u);
            cntC[i]  = 0u;
            offsR[i] = carry2 + s2[tid] - v2;
            cntR[i]  = 0u;
        }
        carry1 += s1[1023];
        carry2 += s2[1023];
        __syncthreads();
    }
    if (tid == 0) { offsC[N_NODES] = carry1; offsR[N_NODES] = carry2; }
}

// build col-CSR (srt_rowC, srt_dstC, permC: col-slot -> row-slot) and row-CSR (srt_srcR, ea_srt)
__global__ void k_scatter(const int* __restrict__ row, const int* __restrict__ col,
                          const float* __restrict__ ea,
                          const unsigned* __restrict__ offsC, unsigned* __restrict__ fillC,
                          const unsigned* __restrict__ offsR, unsigned* __restrict__ fillR,
                          int* __restrict__ srt_rowC, int* __restrict__ srt_dstC,
                          unsigned* __restrict__ permC,
                          int* __restrict__ srt_srcR, float2* __restrict__ ea_srt) {
    int e = blockIdx.x * blockDim.x + threadIdx.x;
    if (e >= N_EDGES) return;
    int r = row[e], c = col[e];
    unsigned pR = offsR[r] + atomicAdd(&fillR[r], 1u);
    srt_srcR[pR] = r;
    ea_srt[pR] = make_float2(ea[2 * e], ea[2 * e + 1]);
    unsigned pC = offsC[c] + atomicAdd(&fillC[c], 1u);
    srt_rowC[pC] = r;
    srt_dstC[pC] = c;
    permC[pC] = pR;
}

// per-layer per-head score constants: M(16) u(4) v(4) w(1) padded to 32, *0.25 folded
__global__ void k_prep(const float* __restrict__ qw, const float* __restrict__ qb,
                       const float* __restrict__ kw, const float* __restrict__ kb,
                       float* __restrict__ cst) {
    int L = blockIdx.x;
    int m = threadIdx.x;
    int d = m & 15;
    const float* qwl = qw + L * 256; const float* kwl = kw + L * 256;
    const float* qbl = qb + L * 64;  const float* kbl = kb + L * 64;
    float qa[4], ka[4];
    #pragma unroll
    for (int a = 0; a < 4; a++) { qa[a] = qwl[a * 64 + m]; ka[a] = kwl[a * 64 + m]; }
    float qbm = qbl[m], kbm = kbl[m];
    float vals[25];
    int idx = 0;
    #pragma unroll
    for (int a = 0; a < 4; a++)
        #pragma unroll
        for (int b = 0; b < 4; b++) vals[idx++] = qa[a] * ka[b];
    #pragma unroll
    for (int a = 0; a < 4; a++) vals[idx++] = qa[a] * kbm;
    #pragma unroll
    for (int b = 0; b < 4; b++) vals[idx++] = qbm * ka[b];
    vals[24] = qbm * kbm;
    #pragma unroll
    for (int i = 0; i < 25; i++) {
        float v = vals[i];
        v += __shfl_xor(v, 1); v += __shfl_xor(v, 2);
        v += __shfl_xor(v, 4); v += __shfl_xor(v, 8);
        vals[i] = v;
    }
    if (d == 0) {
        float* out = cst + L * 128 + (m >> 4) * 32;
        #pragma unroll
        for (int i = 0; i < 25; i++) out[i] = vals[i] * 0.25f;
    }
}

// ---------- per-layer ----------
// 4 nodes per wave: t = h @ rw1[:64] + rb1 ; accum4 self-loop term ; base4
__global__ void k1_node(const float* __restrict__ h, const float* __restrict__ rw1,
                        const float* __restrict__ rb1, const float* __restrict__ rw2,
                        const float* __restrict__ rb2, const float* __restrict__ sw,
                        const float* __restrict__ sb, float* __restrict__ t,
                        float* __restrict__ accum4, float* __restrict__ base4) {
    __shared__ float s_rw2[64][4];
    __shared__ float s_sw[64][4];
    int tid = threadIdx.x;
    { int r = tid >> 2, c = tid & 3; s_rw2[r][c] = rw2[r * 64 + c]; s_sw[r][c] = sw[r * 256 + c]; }
    __syncthreads();
    int wid = (blockIdx.x * blockDim.x + tid) >> 6;
    int lane = tid & 63;
    int n0 = wid * 4;
    if (n0 >= N_NODES) return;
    float hv[4], acc[4];
    #pragma unroll
    for (int i = 0; i < 4; i++) {
        int n = n0 + i;
        hv[i]  = (n < N_NODES) ? h[n * 64 + lane] : 0.f;
        acc[i] = rb1[lane];
    }
    for (int k = 0; k < 64; k++) {
        float w = rw1[k * 64 + lane];
        #pragma unroll
        for (int i = 0; i < 4; i++) acc[i] += __shfl(hv[i], k) * w;
    }
    float rb2_0 = rb2[0] + sb[0], rb2_1 = rb2[1] + sb[1];
    float rb2_2 = rb2[2] + sb[2], rb2_3 = rb2[3] + sb[3];
    #pragma unroll
    for (int i = 0; i < 4; i++) {
        int n = n0 + i;
        if (n >= N_NODES) break;
        t[n * 64 + lane] = acc[i];
        float r = fmaxf(acc[i], 0.f);
        float v0 = r * s_rw2[lane][0], v1 = r * s_rw2[lane][1];
        float v2 = r * s_rw2[lane][2], v3 = r * s_rw2[lane][3];
        float b0 = hv[i] * s_sw[lane][0], b1 = hv[i] * s_sw[lane][1];
        float b2 = hv[i] * s_sw[lane][2], b3 = hv[i] * s_sw[lane][3];
        bsum4(v0, v1, v2, v3);
        bsum4(b0, b1, b2, b3);
        if (lane == 0) {
            ((float4*)accum4)[n] = make_float4(v0, v1, v2, v3);
            ((float4*)base4)[n]  = make_float4(b0 + rb2_0, b1 + rb2_1, b2 + rb2_2, b3 + rb2_3);
        }
    }
}

// one edge per LANE in row-CSR order: stream 4-float contribution to msg4[row_slot].
// No atomics — coalesced 16B store per edge.
__global__ void k2_edge_lane(const int* __restrict__ srt_srcR,
                             const float2* __restrict__ ea_srt, const float* __restrict__ t,
                             const float* __restrict__ rw1, const float* __restrict__ rw2,
                             float4* __restrict__ msg4) {
    int e = blockIdx.x * blockDim.x + threadIdx.x;
    if (e >= N_EDGES) return;
    int src = srt_srcR[e];
    float2 e2 = ea_srt[e];
    const float4* t4 = (const float4*)(t + (size_t)src * 64);
    float v0 = 0.f, v1 = 0.f, v2 = 0.f, v3 = 0.f;
    #pragma unroll
    for (int kc = 0; kc < 16; kc++) {
        float4 tv = t4[kc];
        #pragma unroll
        for (int j = 0; j < 4; j++) {
            int k = kc * 4 + j;
            float tk = (j == 0) ? tv.x : (j == 1) ? tv.y : (j == 2) ? tv.z : tv.w;
            float pre = tk + e2.x * rw1[64 * 64 + k] + e2.y * rw1[65 * 64 + k];
            float rr = fmaxf(pre, 0.f);
            v0 += rr * rw2[k * 64 + 0];
            v1 += rr * rw2[k * 64 + 1];
            v2 += rr * rw2[k * 64 + 2];
            v3 += rr * rw2[k * 64 + 3];
        }
    }
    msg4[e] = make_float4(v0, v1, v2, v3);
}

// col-CSR gather: quarter-wave per dst sums msg4[permC[p]] — exclusive ownership, no atomics
__global__ void k2b_gather(const unsigned* __restrict__ offsC, const unsigned* __restrict__ permC,
                           const float4* __restrict__ msg4, float4* __restrict__ accum4) {
    int tid = threadIdx.x;
    int lane = tid & 63;
    int sub = lane >> 4, l16 = lane & 15;
    int gid = (blockIdx.x * blockDim.x + tid) >> 6;
    int c = gid * 4 + sub;
    if (c >= N_NODES) return;
    int beg = offsC[c], end = offsC[c + 1];
    float a0 = 0.f, a1 = 0.f, a2 = 0.f, a3 = 0.f;
    for (int p = beg + l16; p < end; p += 16) {
        float4 m = msg4[permC[p]];
        a0 += m.x; a1 += m.y; a2 += m.z; a3 += m.w;
    }
    #pragma unroll
    for (int m = 1; m < 16; m <<= 1) {
        a0 += __shfl_xor(a0, m);
        a1 += __shfl_xor(a1, m);
        a2 += __shfl_xor(a2, m);
        a3 += __shfl_xor(a3, m);
    }
    if (l16 == 0) {
        float4 old = accum4[c];   // self-loop term from k1
        accum4[c] = make_float4(old.x + a0, old.y + a1, old.z + a2, old.w + a3);
    }
}

// x4 = accum4/deg + base4 ; P[node][h][j] = sum_d V[h*16+d]*ow[h*16+d][j] ; init mx/sumexp
__global__ void k3_x4P(const float* __restrict__ accum4, const float* __restrict__ base4,
                       const float* __restrict__ deg, float* __restrict__ x4buf,
                       const float* __restrict__ vw, const float* __restrict__ vb,
                       const float* __restrict__ ow, float* __restrict__ P,
                       unsigned* __restrict__ mx_u, float* __restrict__ sumexp) {
    int tid = threadIdx.x;
    if (blockIdx.x == 0 && tid < 4) { mx_u[tid] = 0u; sumexp[tid] = 0.f; }
    int node = (blockIdx.x * blockDim.x + tid) >> 6;
    int lane = tid & 63;
    if (node >= N_NODES) return;
    float4 a = ((const float4*)accum4)[node];
    float4 b = ((const float4*)base4)[node];
    float idg = 1.f / deg[node];
    float x0 = a.x * idg + b.x, x1 = a.y * idg + b.y;
    float x2 = a.z * idg + b.z, x3 = a.w * idg + b.w;
    if (lane == 0) ((float4*)x4buf)[node] = make_float4(x0, x1, x2, x3);
    float vv = vb[lane] + x0 * vw[lane] + x1 * vw[64 + lane]
             + x2 * vw[128 + lane] + x3 * vw[192 + lane];
    float4 owv = ((const float4*)ow)[lane];
    float p0 = vv * owv.x, p1 = vv * owv.y, p2 = vv * owv.z, p3 = vv * owv.w;
    #pragma unroll
    for (int m = 1; m < 16; m <<= 1) {
        p0 += __shfl_xor(p0, m); p1 += __shfl_xor(p1, m);
        p2 += __shfl_xor(p2, m); p3 += __shfl_xor(p3, m);
    }
    int d = lane & 15;
    if (d < 4) {
        float val = (d == 0) ? p0 : (d == 1) ? p1 : (d == 2) ? p2 : p3;
        P[node * 16 + (lane >> 4) * 4 + d] = val;
    }
}

// max-only pass: thread per col-slot, rank-4 bilinear score, per-head global max (no store)
__global__ void k4_scores(const int* __restrict__ srt_rowC, const int* __restrict__ srt_dstC,
                          const float* __restrict__ x4b, const float* __restrict__ cst,
                          unsigned* __restrict__ mx_u) {
    __shared__ float sc[128];
    __shared__ unsigned lmax[4];
    int tid = threadIdx.x;
    if (tid < 128) sc[tid] = cst[tid];
    if (tid < 4) lmax[tid] = 0u;
    __syncthreads();
    int p = blockIdx.x * blockDim.x + tid;
    float m0 = -1e30f, m1 = -1e30f, m2 = -1e30f, m3 = -1e30f;
    if (p < N_EDGES) {
        int r = srt_rowC[p], c = srt_dstC[p];
        float4 xr = ((const float4*)x4b)[r];
        float4 xc = ((const float4*)x4b)[c];
        float s[4];
        #pragma unroll
        for (int h = 0; h < 4; h++) {
            const float* C = &sc[h * 32];
            float g0 = xc.x * C[0]  + xc.y * C[1]  + xc.z * C[2]  + xc.w * C[3]  + C[16];
            float g1 = xc.x * C[4]  + xc.y * C[5]  + xc.z * C[6]  + xc.w * C[7]  + C[17];
            float g2 = xc.x * C[8]  + xc.y * C[9]  + xc.z * C[10] + xc.w * C[11] + C[18];
            float g3 = xc.x * C[12] + xc.y * C[13] + xc.z * C[14] + xc.w * C[15] + C[19];
            s[h] = xr.x * g0 + xr.y * g1 + xr.z * g2 + xr.w * g3
                 + C[20] * xc.x + C[21] * xc.y + C[22] * xc.z + C[23] * xc.w + C[24];
        }
        m0 = s[0]; m1 = s[1]; m2 = s[2]; m3 = s[3];
    }
    #pragma unroll
    for (int m = 1; m < 64; m <<= 1) {
        m0 = fmaxf(m0, __shfl_xor(m0, m));
        m1 = fmaxf(m1, __shfl_xor(m1, m));
        m2 = fmaxf(m2, __shfl_xor(m2, m));
        m3 = fmaxf(m3, __shfl_xor(m3, m));
    }
    if ((tid & 63) == 0) {
        atomicMax(&lmax[0], f2ord(m0));
        atomicMax(&lmax[1], f2ord(m1));
        atomicMax(&lmax[2], f2ord(m2));
        atomicMax(&lmax[3], f2ord(m3));
    }
    __syncthreads();
    if (tid < 4) atomicMax(&mx_u[tid], lmax[tid]);
}

// col-CSR gather with inline score recompute: quarter-wave per dst;
// att16[c][h][j] = sum_e exp(s_e(h)-m_h) * P[r][h][j]
__global__ void k5_att(const unsigned* __restrict__ offsC, const int* __restrict__ srt_rowC,
                       const float* __restrict__ x4b, const float* __restrict__ cst,
                       const unsigned* __restrict__ mx_u, const float* __restrict__ P,
                       float* __restrict__ att16, float* __restrict__ sumexp) {
    __shared__ float lsum[4];
    int tid = threadIdx.x;
    if (tid < 4) lsum[tid] = 0.f;
    __syncthreads();
    int lane = tid & 63;
    int sub = lane >> 4, d = lane & 15, h = d >> 2, j = d & 3;
    const float* C = cst + h * 32;
    float mxh = ord2f(mx_u[h]);
    int gid = (blockIdx.x * blockDim.x + tid) >> 6;
    int c = gid * 4 + sub;
    float acc = 0.f, sume = 0.f;
    if (c < N_NODES) {
        float4 xc = ((const float4*)x4b)[c];
        // per-dst factorization: s = xr . g + base
        float g0 = xc.x * C[0]  + xc.y * C[1]  + xc.z * C[2]  + xc.w * C[3]  + C[16];
        float g1 = xc.x * C[4]  + xc.y * C[5]  + xc.z * C[6]  + xc.w * C[7]  + C[17];
        float g2 = xc.x * C[8]  + xc.y * C[9]  + xc.z * C[10] + xc.w * C[11] + C[18];
        float g3 = xc.x * C[12] + xc.y * C[13] + xc.z * C[14] + xc.w * C[15] + C[19];
        float base = C[20] * xc.x + C[21] * xc.y + C[22] * xc.z + C[23] * xc.w + C[24] - mxh;
        int beg = offsC[c], end = offsC[c + 1];
        for (int p = beg; p < end; p++) {
            int r = srt_rowC[p];
            float4 xr = ((const float4*)x4b)[r];
            float s = xr.x * g0 + xr.y * g1 + xr.z * g2 + xr.w * g3 + base;
            float ex = __expf(s);
            acc += ex * P[r * 16 + d];
            if (j == 0) sume += ex;
        }
        att16[c * 16 + d] = acc;
    }
    sume += __shfl_xor(sume, 16);
    sume += __shfl_xor(sume, 32);
    if (lane < 16 && j == 0) atomicAdd(&lsum[h], sume);
    __syncthreads();
    if (tid < 4) atomicAdd(&sumexp[tid], lsum[tid]);
}

// finalize: y = sum_h att16/Z_h + ob + x4 -> LN -> + residual -> xcur ; h = xcur@in_w+in_b
__global__ void k6_fin(const float* __restrict__ att16, const float* __restrict__ sumexp,
                       const float* __restrict__ x4buf, const float* __restrict__ ob,
                       const float* __restrict__ g, const float* __restrict__ bb,
                       const float* __restrict__ resw, const float* __restrict__ in_w,
                       const float* __restrict__ in_b, float* __restrict__ xcur,
                       float* __restrict__ h) {
    int tid = threadIdx.x;
    int node = (blockIdx.x * blockDim.x + tid) >> 6;
    int lane = tid & 63;
    if (node >= N_NODES) return;
    float z = sumexp[(lane & 15) >> 2];
    float a = 0.f;
    if (lane < 16) a = att16[node * 16 + lane] / z;
    a += __shfl_xor(a, 4);
    a += __shfl_xor(a, 8);
    float y0 = __shfl(a, 0), y1 = __shfl(a, 1), y2 = __shfl(a, 2), y3 = __shfl(a, 3);
    float4 x4v = ((const float4*)x4buf)[node];
    y0 += ob[0] + x4v.x; y1 += ob[1] + x4v.y;
    y2 += ob[2] + x4v.z; y3 += ob[3] + x4v.w;
    float mu = 0.25f * (y0 + y1 + y2 + y3);
    float d0 = y0 - mu, d1 = y1 - mu, d2 = y2 - mu, d3 = y3 - mu;
    float var = 0.25f * (d0 * d0 + d1 * d1 + d2 * d2 + d3 * d3);
    float rs = rsqrtf(var + 1e-5f);
    float4 xold = ((const float4*)xcur)[node];
    float rw = resw[0];
    float n0 = d0 * rs * g[0] + bb[0] + xold.x * rw;
    float n1 = d1 * rs * g[1] + bb[1] + xold.y * rw;
    float n2 = d2 * rs * g[2] + bb[2] + xold.z * rw;
    float n3 = d3 * rs * g[3] + bb[3] + xold.w * rw;
    if (lane == 0) ((float4*)xcur)[node] = make_float4(n0, n1, n2, n3);
    float hv = in_b[lane] + n0 * in_w[lane] + n1 * in_w[64 + lane]
             + n2 * in_w[128 + lane] + n3 * in_w[192 + lane];
    h[node * 64 + lane] = hv;
}

// pred = tanh(relu(h@w1+b1)@w2 + b2) * 0.3
__global__ void k_pred(const float* __restrict__ h, const float* __restrict__ w1,
                       const float* __restrict__ b1, const float* __restrict__ w2,
                       const float* __restrict__ b2, float* __restrict__ out) {
    int tid = threadIdx.x;
    int node = (blockIdx.x * blockDim.x + tid) >> 6;
    int lane = tid & 63;
    if (node >= N_NODES) return;
    int j2 = lane & 31;
    float hv = h[node * 64 + lane];
    float m = b1[j2];
    #pragma unroll 8
    for (int k = 0; k < 64; k++) m += __shfl(hv, k) * w1[k * 32 + j2];
    m = fmaxf(m, 0.f);
    float4 w2v = ((const float4*)w2)[j2];
    float v0 = m * w2v.x, v1 = m * w2v.y, v2 = m * w2v.z, v3 = m * w2v.w;
    bsum4(v0, v1, v2, v3);
    float o0 = tanhf(0.5f * v0 + b2[0]) * 0.3f;
    float o1 = tanhf(0.5f * v1 + b2[1]) * 0.3f;
    float o2 = tanhf(0.5f * v2 + b2[2]) * 0.3f;
    float o3 = tanhf(0.5f * v3 + b2[3]) * 0.3f;
    if (lane == 0) ((float4*)out)[node] = make_float4(o0, o1, o2, o3);
}

// ---------- launch ----------
extern "C" void kernel_launch(void* const* d_in, const int* in_sizes, int n_in,
                              void* d_out, int out_size, void* d_ws, size_t ws_size,
                              hipStream_t stream) {
    const float* x        = (const float*)d_in[0];
    const int*   ei       = (const int*)d_in[1];
    const float* ea       = (const float*)d_in[2];
    const float* in_w     = (const float*)d_in[3];
    const float* in_b     = (const float*)d_in[4];
    const float* conv_rw1 = (const float*)d_in[5];
    const float* conv_rb1 = (const float*)d_in[6];
    const float* conv_rw2 = (const float*)d_in[7];
    const float* conv_rb2 = (const float*)d_in[8];
    // d_in[9..12] (imag path) dead: x4 = h4[:, :4] only touches real[:, :4]
    const float* conv_sw  = (const float*)d_in[13];
    const float* conv_sb  = (const float*)d_in[14];
    const float* att_qw   = (const float*)d_in[15];
    const float* att_qb   = (const float*)d_in[16];
    const float* att_kw   = (const float*)d_in[17];
    const float* att_kb   = (const float*)d_in[18];
    const float* att_vw   = (const float*)d_in[19];
    const float* att_vb   = (const float*)d_in[20];
    const float* att_ow   = (const float*)d_in[21];
    const float* att_ob   = (const float*)d_in[22];
    const float* ln_g     = (const float*)d_in[23];
    const float* ln_b     = (const float*)d_in[24];
    const float* out_w1   = (const float*)d_in[25];
    const float* out_b1   = (const float*)d_in[26];
    const float* out_w2   = (const float*)d_in[27];
    const float* out_b2   = (const float*)d_in[28];
    const float* res_w    = (const float*)d_in[29];

    const int* row = ei;
    const int* col = ei + N_EDGES;

    char* ws = (char*)d_ws;
    size_t off = 0;
    auto alloc = [&](size_t bytes) -> void* {
        void* p = ws + off;
        off = (off + bytes + 255) & ~(size_t)255;
        return p;
    };
    float*    deg      = (float*)alloc(N_NODES * 4);
    unsigned* cntC     = (unsigned*)alloc(N_NODES * 4);
    unsigned* cntR     = (unsigned*)alloc(N_NODES * 4);
    unsigned* offsC    = (unsigned*)alloc((N_NODES + 1) * 4);
    unsigned* offsR    = (unsigned*)alloc((N_NODES + 1) * 4);
    int*      srt_rowC = (int*)alloc((size_t)N_EDGES * 4);
    int*      srt_dstC = (int*)alloc((size_t)N_EDGES * 4);
    unsigned* permC    = (unsigned*)alloc((size_t)N_EDGES * 4);
    int*      srt_srcR = (int*)alloc((size_t)N_EDGES * 4);
    float2*   ea_srt   = (float2*)alloc((size_t)N_EDGES * 8);
    float4*   msg4     = (float4*)alloc((size_t)N_EDGES * 16);
    float*    tbuf     = (float*)alloc((size_t)N_NODES * 64 * 4);
    float*    hb       = (float*)alloc((size_t)N_NODES * 64 * 4);
    float*    Pbuf     = (float*)alloc((size_t)N_NODES * 16 * 4);
    float*    att16    = (float*)alloc((size_t)N_NODES * 16 * 4);
    float4*   accum4   = (float4*)alloc((size_t)N_NODES * 16);
    float*    base4    = (float*)alloc(N_NODES * 4 * 4);
    float*    x4b      = (float*)alloc(N_NODES * 4 * 4);
    float*    xcur     = (float*)alloc(N_NODES * 4 * 4);
    float*    cst      = (float*)alloc(4 * 128 * 4);
    unsigned* mx_u     = (unsigned*)alloc(256);
    float*    sumexp   = (float*)alloc(256);

    dim3 b256(256);
    int nodeBlocks  = (N_NODES + 3) / 4;        // wave per node
    int nodeBlocks4 = (N_NODES + 15) / 16;      // wave per 4 nodes
    int edgeTB      = (N_EDGES + 255) / 256;    // thread per edge
    int dstBlocks   = (N_NODES + 15) / 16;      // quarter-wave per dst

    k_h0<<<nodeBlocks, b256, 0, stream>>>(x, in_w, in_b, hb, xcur, cntC, cntR);
    k_count<<<edgeTB, b256, 0, stream>>>(row, col, cntR, cntC);
    k_scan<<<1, 1024, 0, stream>>>(cntC, offsC, deg, cntR, offsR);
    k_scatter<<<edgeTB, b256, 0, stream>>>(row, col, ea, offsC, cntC, offsR, cntR,
                                           srt_rowC, srt_dstC, permC, srt_srcR, ea_srt);
    k_prep<<<4, 64, 0, stream>>>(att_qw, att_qb, att_kw, att_kb, cst);

    for (int i = 0; i < 4; i++) {
        const float* rw1 = conv_rw1 + i * 66 * 64;
        const float* rb1 = conv_rb1 + i * 64;
        const float* rw2 = conv_rw2 + i * 64 * 64;
        const float* rb2 = conv_rb2 + i * 64;
        const float* swl = conv_sw + i * 64 * 256;
        const float* sbl = conv_sb + i * 256;

        k1_node<<<nodeBlocks4, b256, 0, stream>>>(hb, rw1, rb1, rw2, rb2, swl, sbl,
                                                  tbuf, (float*)accum4, base4);
        k2_edge_lane<<<edgeTB, b256, 0, stream>>>(srt_srcR, ea_srt, tbuf,
                                                  rw1, rw2, msg4);
        k2b_gather<<<dstBlocks, b256, 0, stream>>>(offsC, permC, msg4, accum4);
        k3_x4P<<<nodeBlocks, b256, 0, stream>>>((const float*)accum4, base4, deg, x4b,
                                                att_vw + i * 256, att_vb + i * 64,
                                                att_ow + i * 256, Pbuf, mx_u, sumexp);
        k4_scores<<<edgeTB, b256, 0, stream>>>(srt_rowC, srt_dstC, x4b, cst + i * 128, mx_u);
        k5_att<<<dstBlocks, b256, 0, stream>>>(offsC, srt_rowC, x4b, cst + i * 128,
                                               mx_u, Pbuf, att16, sumexp);
        k6_fin<<<nodeBlocks, b256, 0, stream>>>(att16, sumexp, x4b,
                                                att_ob + i * 4, ln_g + i * 4,
                                                ln_b + i * 4, res_w + i,
                                                in_w, in_b, xcur, hb);
    }
    k_pred<<<nodeBlocks, b256, 0, stream>>>(hb, out_w1, out_b1, out_w2, out_b2, (float*)d_out);
}

// Round 5
// 975.013 us; speedup vs baseline: 2.5009x; 1.3163x over previous
//
#include <hip/hip_runtime.h>
#include <hip/hip_bf16.h>

#define N_NODES 50000
#define N_EDGES 800000
#define SCAN_NB ((N_NODES + 1023) / 1024)   // 49

// ---------- helpers ----------
__device__ __forceinline__ void bsum4(float& v0, float& v1, float& v2, float& v3) {
    #pragma unroll
    for (int m = 1; m < 64; m <<= 1) {
        v0 += __shfl_xor(v0, m);
        v1 += __shfl_xor(v1, m);
        v2 += __shfl_xor(v2, m);
        v3 += __shfl_xor(v3, m);
    }
}

// ---------- setup ----------
__global__ void k_h0(const float* __restrict__ x, const float* __restrict__ in_w,
                     const float* __restrict__ in_b, float* __restrict__ h,
                     float4* __restrict__ xcur, unsigned* __restrict__ cntC,
                     unsigned* __restrict__ cntR) {
    int node = (blockIdx.x * blockDim.x + threadIdx.x) >> 6;
    int lane = threadIdx.x & 63;
    if (node >= N_NODES) return;
    float4 xv = ((const float4*)x)[node];
    float hv = in_b[lane] + xv.x * in_w[lane] + xv.y * in_w[64 + lane]
             + xv.z * in_w[128 + lane] + xv.w * in_w[192 + lane];
    h[node * 64 + lane] = hv;
    if (lane == 0) { xcur[node] = xv; cntC[node] = 0u; cntR[node] = 0u; }
}

__global__ void k_count(const int* __restrict__ row, const int* __restrict__ col,
                        unsigned* __restrict__ cntR, unsigned* __restrict__ cntC) {
    int e = blockIdx.x * blockDim.x + threadIdx.x;
    if (e < N_EDGES) {
        atomicAdd(&cntR[row[e]], 1u);
        atomicAdd(&cntC[col[e]], 1u);
    }
}

// block-level exclusive scan of both count arrays; emits per-block sums
__global__ void __launch_bounds__(1024) k_scanA(unsigned* __restrict__ cntC,
                                                unsigned* __restrict__ offsC,
                                                float* __restrict__ deg,
                                                unsigned* __restrict__ cntR,
                                                unsigned* __restrict__ offsR,
                                                unsigned* __restrict__ bs1,
                                                unsigned* __restrict__ bs2) {
    __shared__ unsigned s1[1024];
    __shared__ unsigned s2[1024];
    int tid = threadIdx.x;
    int i = blockIdx.x * 1024 + tid;
    unsigned v1 = (i < N_NODES) ? cntC[i] : 0u;
    unsigned v2 = (i < N_NODES) ? cntR[i] : 0u;
    s1[tid] = v1; s2[tid] = v2;
    __syncthreads();
    for (int off = 1; off < 1024; off <<= 1) {
        unsigned t1 = (tid >= off) ? s1[tid - off] : 0u;
        unsigned t2 = (tid >= off) ? s2[tid - off] : 0u;
        __syncthreads();
        s1[tid] += t1; s2[tid] += t2;
        __syncthreads();
    }
    if (i < N_NODES) {
        offsC[i] = s1[tid] - v1;
        offsR[i] = s2[tid] - v2;
        deg[i]   = (float)(v1 + 1u);   // + self loop
        cntC[i]  = 0u;
        cntR[i]  = 0u;
    }
    if (tid == 1023) { bs1[blockIdx.x] = s1[1023]; bs2[blockIdx.x] = s2[1023]; }
}

// single-wave scan of the SCAN_NB block sums -> carries + totals
__global__ void k_scanB(const unsigned* __restrict__ bs1, const unsigned* __restrict__ bs2,
                        unsigned* __restrict__ carry1, unsigned* __restrict__ carry2,
                        unsigned* __restrict__ offsC, unsigned* __restrict__ offsR) {
    int lane = threadIdx.x;  // 64 threads
    unsigned v1 = (lane < SCAN_NB) ? bs1[lane] : 0u;
    unsigned v2 = (lane < SCAN_NB) ? bs2[lane] : 0u;
    unsigned i1 = v1, i2 = v2;
    #pragma unroll
    for (int off = 1; off < 64; off <<= 1) {
        unsigned t1 = __shfl_up(i1, off);
        unsigned t2 = __shfl_up(i2, off);
        if (lane >= off) { i1 += t1; i2 += t2; }
    }
    if (lane < SCAN_NB) { carry1[lane] = i1 - v1; carry2[lane] = i2 - v2; }
    if (lane == SCAN_NB - 1) { offsC[N_NODES] = i1; offsR[N_NODES] = i2; }
}

__global__ void __launch_bounds__(1024) k_scanC(unsigned* __restrict__ offsC,
                                                unsigned* __restrict__ offsR,
                                                const unsigned* __restrict__ carry1,
                                                const unsigned* __restrict__ carry2) {
    int b = blockIdx.x;
    int i = b * 1024 + threadIdx.x;
    if (i < N_NODES) { offsC[i] += carry1[b]; offsR[i] += carry2[b]; }
}

// build col-CSR (srt_rowC, permC: col-slot -> row-slot) and row-CSR (srt_srcR, ea_srt)
__global__ void k_scatter(const int* __restrict__ row, const int* __restrict__ col,
                          const float* __restrict__ ea,
                          const unsigned* __restrict__ offsC, unsigned* __restrict__ fillC,
                          const unsigned* __restrict__ offsR, unsigned* __restrict__ fillR,
                          int* __restrict__ srt_rowC, unsigned* __restrict__ permC,
                          int* __restrict__ srt_srcR, float2* __restrict__ ea_srt) {
    int e = blockIdx.x * blockDim.x + threadIdx.x;
    if (e >= N_EDGES) return;
    int r = row[e], c = col[e];
    unsigned pR = offsR[r] + atomicAdd(&fillR[r], 1u);
    srt_srcR[pR] = r;
    ea_srt[pR] = make_float2(ea[2 * e], ea[2 * e + 1]);
    unsigned pC = offsC[c] + atomicAdd(&fillC[c], 1u);
    srt_rowC[pC] = r;
    permC[pC] = pR;
}

// per-layer per-head score constants: M(16) u(4) v(4) w(1) padded to 32, *0.25 folded
__global__ void k_prep(const float* __restrict__ qw, const float* __restrict__ qb,
                       const float* __restrict__ kw, const float* __restrict__ kb,
                       float* __restrict__ cst) {
    int L = blockIdx.x;
    int m = threadIdx.x;
    int d = m & 15;
    const float* qwl = qw + L * 256; const float* kwl = kw + L * 256;
    const float* qbl = qb + L * 64;  const float* kbl = kb + L * 64;
    float qa[4], ka[4];
    #pragma unroll
    for (int a = 0; a < 4; a++) { qa[a] = qwl[a * 64 + m]; ka[a] = kwl[a * 64 + m]; }
    float qbm = qbl[m], kbm = kbl[m];
    float vals[25];
    int idx = 0;
    #pragma unroll
    for (int a = 0; a < 4; a++)
        #pragma unroll
        for (int b = 0; b < 4; b++) vals[idx++] = qa[a] * ka[b];
    #pragma unroll
    for (int a = 0; a < 4; a++) vals[idx++] = qa[a] * kbm;
    #pragma unroll
    for (int b = 0; b < 4; b++) vals[idx++] = qbm * ka[b];
    vals[24] = qbm * kbm;
    #pragma unroll
    for (int i = 0; i < 25; i++) {
        float v = vals[i];
        v += __shfl_xor(v, 1); v += __shfl_xor(v, 2);
        v += __shfl_xor(v, 4); v += __shfl_xor(v, 8);
        vals[i] = v;
    }
    if (d == 0) {
        float* out = cst + L * 128 + (m >> 4) * 32;
        #pragma unroll
        for (int i = 0; i < 25; i++) out[i] = vals[i] * 0.25f;
    }
}

// ---------- per-layer ----------
// layer-0 only: t = h @ rw1[:64] + rb1 ; accum4 self-loop term ; base4
__global__ void k1_node(const float* __restrict__ h, const float* __restrict__ rw1,
                        const float* __restrict__ rb1, const float* __restrict__ rw2,
                        const float* __restrict__ rb2, const float* __restrict__ sw,
                        const float* __restrict__ sb, float* __restrict__ t,
                        float4* __restrict__ accum4, float4* __restrict__ base4) {
    __shared__ float s_rw2[64][4];
    __shared__ float s_sw[64][4];
    int tid = threadIdx.x;
    { int r = tid >> 2, c = tid & 3; s_rw2[r][c] = rw2[r * 64 + c]; s_sw[r][c] = sw[r * 256 + c]; }
    __syncthreads();
    int wid = (blockIdx.x * blockDim.x + tid) >> 6;
    int lane = tid & 63;
    int n0 = wid * 4;
    if (n0 >= N_NODES) return;
    float hv[4], acc[4];
    #pragma unroll
    for (int i = 0; i < 4; i++) {
        int n = n0 + i;
        hv[i]  = (n < N_NODES) ? h[n * 64 + lane] : 0.f;
        acc[i] = rb1[lane];
    }
    for (int k = 0; k < 64; k++) {
        float w = rw1[k * 64 + lane];
        #pragma unroll
        for (int i = 0; i < 4; i++) acc[i] += __shfl(hv[i], k) * w;
    }
    float rb2_0 = rb2[0] + sb[0], rb2_1 = rb2[1] + sb[1];
    float rb2_2 = rb2[2] + sb[2], rb2_3 = rb2[3] + sb[3];
    #pragma unroll
    for (int i = 0; i < 4; i++) {
        int n = n0 + i;
        if (n >= N_NODES) break;
        t[n * 64 + lane] = acc[i];
        float r = fmaxf(acc[i], 0.f);
        float v0 = r * s_rw2[lane][0], v1 = r * s_rw2[lane][1];
        float v2 = r * s_rw2[lane][2], v3 = r * s_rw2[lane][3];
        float b0 = hv[i] * s_sw[lane][0], b1 = hv[i] * s_sw[lane][1];
        float b2 = hv[i] * s_sw[lane][2], b3 = hv[i] * s_sw[lane][3];
        bsum4(v0, v1, v2, v3);
        bsum4(b0, b1, b2, b3);
        if (lane == 0) {
            accum4[n] = make_float4(v0, v1, v2, v3);
            base4[n]  = make_float4(b0 + rb2_0, b1 + rb2_1, b2 + rb2_2, b3 + rb2_3);
        }
    }
}

// layers 1..3: finalize prev layer (softmax-normalize, out-proj, LN, residual) and
// compute this layer's t / accum4 / base4 — h never leaves registers.
__global__ void k61(const float* __restrict__ att16, const float* __restrict__ sumexp,
                    const float4* __restrict__ x4b, const float* __restrict__ ob,
                    const float* __restrict__ g, const float* __restrict__ bb,
                    const float* __restrict__ resw, const float* __restrict__ in_w,
                    const float* __restrict__ in_b, float4* __restrict__ xcur,
                    const float* __restrict__ rw1, const float* __restrict__ rb1,
                    const float* __restrict__ rw2, const float* __restrict__ rb2,
                    const float* __restrict__ sw, const float* __restrict__ sb,
                    float* __restrict__ t, float4* __restrict__ accum4,
                    float4* __restrict__ base4) {
    __shared__ float s_rw2[64][4];
    __shared__ float s_sw[64][4];
    int tid = threadIdx.x;
    { int r = tid >> 2, c = tid & 3; s_rw2[r][c] = rw2[r * 64 + c]; s_sw[r][c] = sw[r * 256 + c]; }
    __syncthreads();
    int wid = (blockIdx.x * blockDim.x + tid) >> 6;
    int lane = tid & 63;
    int n0 = wid * 4;
    if (n0 >= N_NODES) return;
    float iw0 = in_w[lane], iw1 = in_w[64 + lane], iw2 = in_w[128 + lane], iw3 = in_w[192 + lane];
    float ibl = in_b[lane];
    float z = sumexp[(lane & 15) >> 2];
    float ob0 = ob[0], ob1 = ob[1], ob2 = ob[2], ob3 = ob[3];
    float g0 = g[0], g1 = g[1], g2 = g[2], g3 = g[3];
    float bb0 = bb[0], bb1 = bb[1], bb2 = bb[2], bb3 = bb[3];
    float rw = resw[0];
    float hv[4];
    #pragma unroll
    for (int i = 0; i < 4; i++) {
        int n = n0 + i;
        float a = 0.f;
        if (n < N_NODES && lane < 16) a = att16[n * 16 + lane] / z;
        a += __shfl_xor(a, 4);
        a += __shfl_xor(a, 8);
        float y0 = __shfl(a, 0), y1 = __shfl(a, 1), y2 = __shfl(a, 2), y3 = __shfl(a, 3);
        hv[i] = 0.f;
        if (n < N_NODES) {
            float4 x4v = x4b[n];
            y0 += ob0 + x4v.x; y1 += ob1 + x4v.y;
            y2 += ob2 + x4v.z; y3 += ob3 + x4v.w;
            float mu = 0.25f * (y0 + y1 + y2 + y3);
            float d0 = y0 - mu, d1 = y1 - mu, d2 = y2 - mu, d3 = y3 - mu;
            float var = 0.25f * (d0 * d0 + d1 * d1 + d2 * d2 + d3 * d3);
            float rs = rsqrtf(var + 1e-5f);
            float4 xold = xcur[n];
            float nn0 = d0 * rs * g0 + bb0 + xold.x * rw;
            float nn1 = d1 * rs * g1 + bb1 + xold.y * rw;
            float nn2 = d2 * rs * g2 + bb2 + xold.z * rw;
            float nn3 = d3 * rs * g3 + bb3 + xold.w * rw;
            if (lane == 0) xcur[n] = make_float4(nn0, nn1, nn2, nn3);
            hv[i] = ibl + nn0 * iw0 + nn1 * iw1 + nn2 * iw2 + nn3 * iw3;
        }
    }
    float acc[4];
    #pragma unroll
    for (int i = 0; i < 4; i++) acc[i] = rb1[lane];
    for (int k = 0; k < 64; k++) {
        float w = rw1[k * 64 + lane];
        #pragma unroll
        for (int i = 0; i < 4; i++) acc[i] += __shfl(hv[i], k) * w;
    }
    float rb2_0 = rb2[0] + sb[0], rb2_1 = rb2[1] + sb[1];
    float rb2_2 = rb2[2] + sb[2], rb2_3 = rb2[3] + sb[3];
    #pragma unroll
    for (int i = 0; i < 4; i++) {
        int n = n0 + i;
        if (n >= N_NODES) break;
        t[n * 64 + lane] = acc[i];
        float r = fmaxf(acc[i], 0.f);
        float v0 = r * s_rw2[lane][0], v1 = r * s_rw2[lane][1];
        float v2 = r * s_rw2[lane][2], v3 = r * s_rw2[lane][3];
        float b0 = hv[i] * s_sw[lane][0], b1 = hv[i] * s_sw[lane][1];
        float b2 = hv[i] * s_sw[lane][2], b3 = hv[i] * s_sw[lane][3];
        bsum4(v0, v1, v2, v3);
        bsum4(b0, b1, b2, b3);
        if (lane == 0) {
            accum4[n] = make_float4(v0, v1, v2, v3);
            base4[n]  = make_float4(b0 + rb2_0, b1 + rb2_1, b2 + rb2_2, b3 + rb2_3);
        }
    }
}

// one edge per LANE in row-CSR order: stream 4-float contribution to msg4[row_slot]
__global__ void k2_edge_lane(const int* __restrict__ srt_srcR,
                             const float2* __restrict__ ea_srt, const float* __restrict__ t,
                             const float* __restrict__ rw1, const float* __restrict__ rw2,
                             float4* __restrict__ msg4) {
    int e = blockIdx.x * blockDim.x + threadIdx.x;
    if (e >= N_EDGES) return;
    int src = srt_srcR[e];
    float2 e2 = ea_srt[e];
    const float4* t4 = (const float4*)(t + (size_t)src * 64);
    float v0 = 0.f, v1 = 0.f, v2 = 0.f, v3 = 0.f;
    #pragma unroll
    for (int kc = 0; kc < 16; kc++) {
        float4 tv = t4[kc];
        #pragma unroll
        for (int j = 0; j < 4; j++) {
            int k = kc * 4 + j;
            float tk = (j == 0) ? tv.x : (j == 1) ? tv.y : (j == 2) ? tv.z : tv.w;
            float pre = tk + e2.x * rw1[64 * 64 + k] + e2.y * rw1[65 * 64 + k];
            float rr = fmaxf(pre, 0.f);
            v0 += rr * rw2[k * 64 + 0];
            v1 += rr * rw2[k * 64 + 1];
            v2 += rr * rw2[k * 64 + 2];
            v3 += rr * rw2[k * 64 + 3];
        }
    }
    msg4[e] = make_float4(v0, v1, v2, v3);
}

// fused gather + x4 + P: quarter-wave per dst. Sums msg4[permC[p]], adds self-loop,
// x4 = accum/deg + base4 ; P[c][h][j] = sum_d V[h*16+d]*ow[h*16+d][j] ; sumexp init
__global__ void k23b(const unsigned* __restrict__ offsC, const unsigned* __restrict__ permC,
                     const float4* __restrict__ msg4, const float4* __restrict__ accum4,
                     const float4* __restrict__ base4, const float* __restrict__ deg,
                     float4* __restrict__ x4b, const float* __restrict__ vw,
                     const float* __restrict__ vb, const float* __restrict__ ow,
                     float* __restrict__ P, float* __restrict__ sumexp) {
    int tid = threadIdx.x;
    if (blockIdx.x == 0 && tid < 4) sumexp[tid] = 0.f;
    int lane = tid & 63;
    int sub = lane >> 4, l16 = lane & 15;
    int gid = (blockIdx.x * blockDim.x + tid) >> 6;
    int c = gid * 4 + sub;
    if (c >= N_NODES) return;
    int beg = offsC[c], end = offsC[c + 1];
    float a0 = 0.f, a1 = 0.f, a2 = 0.f, a3 = 0.f;
    for (int p = beg + l16; p < end; p += 16) {
        float4 m = msg4[permC[p]];
        a0 += m.x; a1 += m.y; a2 += m.z; a3 += m.w;
    }
    #pragma unroll
    for (int m = 1; m < 16; m <<= 1) {
        a0 += __shfl_xor(a0, m);
        a1 += __shfl_xor(a1, m);
        a2 += __shfl_xor(a2, m);
        a3 += __shfl_xor(a3, m);
    }
    float4 sl = accum4[c];
    float4 b4 = base4[c];
    float idg = 1.f / deg[c];
    float x0 = (a0 + sl.x) * idg + b4.x;
    float x1 = (a1 + sl.y) * idg + b4.y;
    float x2 = (a2 + sl.z) * idg + b4.z;
    float x3 = (a3 + sl.w) * idg + b4.w;
    if (l16 == 0) x4b[c] = make_float4(x0, x1, x2, x3);
    float part0 = 0.f, part1 = 0.f, part2 = 0.f, part3 = 0.f;
    #pragma unroll
    for (int j = 0; j < 4; j++) {
        int ch = l16 * 4 + j;
        float vv = vb[ch] + x0 * vw[ch] + x1 * vw[64 + ch] + x2 * vw[128 + ch] + x3 * vw[192 + ch];
        float4 owv = ((const float4*)ow)[ch];
        part0 += vv * owv.x; part1 += vv * owv.y;
        part2 += vv * owv.z; part3 += vv * owv.w;
    }
    #pragma unroll
    for (int m = 1; m < 4; m <<= 1) {
        part0 += __shfl_xor(part0, m);
        part1 += __shfl_xor(part1, m);
        part2 += __shfl_xor(part2, m);
        part3 += __shfl_xor(part3, m);
    }
    int j = l16 & 3;
    float val = (j == 0) ? part0 : (j == 1) ? part1 : (j == 2) ? part2 : part3;
    P[c * 16 + l16] = val;
}

// col-CSR gather with inline score recompute (no max subtraction — scores are O(1)):
// att16[c][h][j] = sum_e exp(s_e(h)) * P[r][h][j] ; sumexp += per-head partials
__global__ void k5_att(const unsigned* __restrict__ offsC, const int* __restrict__ srt_rowC,
                       const float4* __restrict__ x4b, const float* __restrict__ cst,
                       const float* __restrict__ P, float* __restrict__ att16,
                       float* __restrict__ sumexp) {
    __shared__ float lsum[4];
    int tid = threadIdx.x;
    if (tid < 4) lsum[tid] = 0.f;
    __syncthreads();
    int lane = tid & 63;
    int sub = lane >> 4, d = lane & 15, h = d >> 2, j = d & 3;
    const float* C = cst + h * 32;
    int gid = (blockIdx.x * blockDim.x + tid) >> 6;
    int c = gid * 4 + sub;
    float sume = 0.f;
    if (c < N_NODES) {
        float4 xc = x4b[c];
        float g0 = xc.x * C[0]  + xc.y * C[1]  + xc.z * C[2]  + xc.w * C[3]  + C[16];
        float g1 = xc.x * C[4]  + xc.y * C[5]  + xc.z * C[6]  + xc.w * C[7]  + C[17];
        float g2 = xc.x * C[8]  + xc.y * C[9]  + xc.z * C[10] + xc.w * C[11] + C[18];
        float g3 = xc.x * C[12] + xc.y * C[13] + xc.z * C[14] + xc.w * C[15] + C[19];
        float base = C[20] * xc.x + C[21] * xc.y + C[22] * xc.z + C[23] * xc.w + C[24];
        int beg = offsC[c], end = offsC[c + 1];
        float acc = 0.f;
        for (int p = beg; p < end; p++) {
            int r = srt_rowC[p];
            float4 xr = x4b[r];
            float s = xr.x * g0 + xr.y * g1 + xr.z * g2 + xr.w * g3 + base;
            float ex = __expf(s);
            acc += ex * P[r * 16 + d];
            if (j == 0) sume += ex;
        }
        att16[c * 16 + d] = acc;
    }
    sume += __shfl_xor(sume, 16);
    sume += __shfl_xor(sume, 32);
    if (lane < 16 && j == 0) atomicAdd(&lsum[h], sume);
    __syncthreads();
    if (tid < 4) atomicAdd(&sumexp[tid], lsum[tid]);
}

// final: finalize layer 3 (softmax-normalize, out-proj, LN, residual, h) then MLP head
__global__ void k6pred(const float* __restrict__ att16, const float* __restrict__ sumexp,
                       const float4* __restrict__ x4b, const float* __restrict__ ob,
                       const float* __restrict__ g, const float* __restrict__ bb,
                       const float* __restrict__ resw, const float4* __restrict__ xcur,
                       const float* __restrict__ in_w, const float* __restrict__ in_b,
                       const float* __restrict__ w1, const float* __restrict__ b1,
                       const float* __restrict__ w2, const float* __restrict__ b2,
                       float* __restrict__ out) {
    int tid = threadIdx.x;
    int node = (blockIdx.x * blockDim.x + tid) >> 6;
    int lane = tid & 63;
    if (node >= N_NODES) return;
    float z = sumexp[(lane & 15) >> 2];
    float a = 0.f;
    if (lane < 16) a = att16[node * 16 + lane] / z;
    a += __shfl_xor(a, 4);
    a += __shfl_xor(a, 8);
    float y0 = __shfl(a, 0), y1 = __shfl(a, 1), y2 = __shfl(a, 2), y3 = __shfl(a, 3);
    float4 x4v = x4b[node];
    y0 += ob[0] + x4v.x; y1 += ob[1] + x4v.y;
    y2 += ob[2] + x4v.z; y3 += ob[3] + x4v.w;
    float mu = 0.25f * (y0 + y1 + y2 + y3);
    float d0 = y0 - mu, d1 = y1 - mu, d2 = y2 - mu, d3 = y3 - mu;
    float var = 0.25f * (d0 * d0 + d1 * d1 + d2 * d2 + d3 * d3);
    float rs = rsqrtf(var + 1e-5f);
    float4 xold = xcur[node];
    float rw = resw[0];
    float n0 = d0 * rs * g[0] + bb[0] + xold.x * rw;
    float n1 = d1 * rs * g[1] + bb[1] + xold.y * rw;
    float n2 = d2 * rs * g[2] + bb[2] + xold.z * rw;
    float n3 = d3 * rs * g[3] + bb[3] + xold.w * rw;
    float hv = in_b[lane] + n0 * in_w[lane] + n1 * in_w[64 + lane]
             + n2 * in_w[128 + lane] + n3 * in_w[192 + lane];
    int j2 = lane & 31;
    float m = b1[j2];
    #pragma unroll 8
    for (int k = 0; k < 64; k++) m += __shfl(hv, k) * w1[k * 32 + j2];
    m = fmaxf(m, 0.f);
    float4 w2v = ((const float4*)w2)[j2];
    float v0 = m * w2v.x, v1 = m * w2v.y, v2 = m * w2v.z, v3 = m * w2v.w;
    bsum4(v0, v1, v2, v3);  // each j2 counted twice (both halves) -> *0.5
    float o0 = tanhf(0.5f * v0 + b2[0]) * 0.3f;
    float o1 = tanhf(0.5f * v1 + b2[1]) * 0.3f;
    float o2 = tanhf(0.5f * v2 + b2[2]) * 0.3f;
    float o3 = tanhf(0.5f * v3 + b2[3]) * 0.3f;
    if (lane == 0) ((float4*)out)[node] = make_float4(o0, o1, o2, o3);
}

// ---------- launch ----------
extern "C" void kernel_launch(void* const* d_in, const int* in_sizes, int n_in,
                              void* d_out, int out_size, void* d_ws, size_t ws_size,
                              hipStream_t stream) {
    const float* x        = (const float*)d_in[0];
    const int*   ei       = (const int*)d_in[1];
    const float* ea       = (const float*)d_in[2];
    const float* in_w     = (const float*)d_in[3];
    const float* in_b     = (const float*)d_in[4];
    const float* conv_rw1 = (const float*)d_in[5];
    const float* conv_rb1 = (const float*)d_in[6];
    const float* conv_rw2 = (const float*)d_in[7];
    const float* conv_rb2 = (const float*)d_in[8];
    // d_in[9..12] (imag path) dead: x4 = h4[:, :4] only touches real[:, :4]
    const float* conv_sw  = (const float*)d_in[13];
    const float* conv_sb  = (const float*)d_in[14];
    const float* att_qw   = (const float*)d_in[15];
    const float* att_qb   = (const float*)d_in[16];
    const float* att_kw   = (const float*)d_in[17];
    const float* att_kb   = (const float*)d_in[18];
    const float* att_vw   = (const float*)d_in[19];
    const float* att_vb   = (const float*)d_in[20];
    const float* att_ow   = (const float*)d_in[21];
    const float* att_ob   = (const float*)d_in[22];
    const float* ln_g     = (const float*)d_in[23];
    const float* ln_b     = (const float*)d_in[24];
    const float* out_w1   = (const float*)d_in[25];
    const float* out_b1   = (const float*)d_in[26];
    const float* out_w2   = (const float*)d_in[27];
    const float* out_b2   = (const float*)d_in[28];
    const float* res_w    = (const float*)d_in[29];

    const int* row = ei;
    const int* col = ei + N_EDGES;

    char* ws = (char*)d_ws;
    size_t off = 0;
    auto alloc = [&](size_t bytes) -> void* {
        void* p = ws + off;
        off = (off + bytes + 255) & ~(size_t)255;
        return p;
    };
    float*    deg      = (float*)alloc(N_NODES * 4);
    unsigned* cntC     = (unsigned*)alloc(N_NODES * 4);
    unsigned* cntR     = (unsigned*)alloc(N_NODES * 4);
    unsigned* offsC    = (unsigned*)alloc((N_NODES + 1) * 4);
    unsigned* offsR    = (unsigned*)alloc((N_NODES + 1) * 4);
    unsigned* bs1      = (unsigned*)alloc(SCAN_NB * 4);
    unsigned* bs2      = (unsigned*)alloc(SCAN_NB * 4);
    unsigned* carry1   = (unsigned*)alloc(SCAN_NB * 4);
    unsigned* carry2   = (unsigned*)alloc(SCAN_NB * 4);
    int*      srt_rowC = (int*)alloc((size_t)N_EDGES * 4);
    unsigned* permC    = (unsigned*)alloc((size_t)N_EDGES * 4);
    int*      srt_srcR = (int*)alloc((size_t)N_EDGES * 4);
    float2*   ea_srt   = (float2*)alloc((size_t)N_EDGES * 8);
    float4*   msg4     = (float4*)alloc((size_t)N_EDGES * 16);
    float*    tbuf     = (float*)alloc((size_t)N_NODES * 64 * 4);
    float*    hb       = (float*)alloc((size_t)N_NODES * 64 * 4);
    float*    Pbuf     = (float*)alloc((size_t)N_NODES * 16 * 4);
    float*    att16    = (float*)alloc((size_t)N_NODES * 16 * 4);
    float4*   accum4   = (float4*)alloc((size_t)N_NODES * 16);
    float4*   base4    = (float4*)alloc((size_t)N_NODES * 16);
    float4*   x4b      = (float4*)alloc((size_t)N_NODES * 16);
    float4*   xcur     = (float4*)alloc((size_t)N_NODES * 16);
    float*    cst      = (float*)alloc(4 * 128 * 4);
    float*    sumexp   = (float*)alloc(256);

    dim3 b256(256);
    int nodeBlocks  = (N_NODES + 3) / 4;        // wave per node
    int nodeBlocks4 = (N_NODES + 15) / 16;      // wave per 4 nodes
    int edgeTB      = (N_EDGES + 255) / 256;    // thread per edge
    int dstBlocks   = (N_NODES + 15) / 16;      // quarter-wave per dst

    k_h0<<<nodeBlocks, b256, 0, stream>>>(x, in_w, in_b, hb, xcur, cntC, cntR);
    k_count<<<edgeTB, b256, 0, stream>>>(row, col, cntR, cntC);
    k_scanA<<<SCAN_NB, 1024, 0, stream>>>(cntC, offsC, deg, cntR, offsR, bs1, bs2);
    k_scanB<<<1, 64, 0, stream>>>(bs1, bs2, carry1, carry2, offsC, offsR);
    k_scanC<<<SCAN_NB, 1024, 0, stream>>>(offsC, offsR, carry1, carry2);
    k_scatter<<<edgeTB, b256, 0, stream>>>(row, col, ea, offsC, cntC, offsR, cntR,
                                           srt_rowC, permC, srt_srcR, ea_srt);
    k_prep<<<4, 64, 0, stream>>>(att_qw, att_qb, att_kw, att_kb, cst);

    for (int i = 0; i < 4; i++) {
        const float* rw1 = conv_rw1 + i * 66 * 64;
        const float* rb1 = conv_rb1 + i * 64;
        const float* rw2 = conv_rw2 + i * 64 * 64;
        const float* rb2 = conv_rb2 + i * 64;
        const float* swl = conv_sw + i * 64 * 256;
        const float* sbl = conv_sb + i * 256;

        if (i == 0) {
            k1_node<<<nodeBlocks4, b256, 0, stream>>>(hb, rw1, rb1, rw2, rb2, swl, sbl,
                                                      tbuf, accum4, base4);
        } else {
            k61<<<nodeBlocks4, b256, 0, stream>>>(att16, sumexp, x4b,
                                                  att_ob + (i - 1) * 4, ln_g + (i - 1) * 4,
                                                  ln_b + (i - 1) * 4, res_w + (i - 1),
                                                  in_w, in_b, xcur,
                                                  rw1, rb1, rw2, rb2, swl, sbl,
                                                  tbuf, accum4, base4);
        }
        k2_edge_lane<<<edgeTB, b256, 0, stream>>>(srt_srcR, ea_srt, tbuf, rw1, rw2, msg4);
        k23b<<<dstBlocks, b256, 0, stream>>>(offsC, permC, msg4, accum4, base4, deg,
                                             x4b, att_vw + i * 256, att_vb + i * 64,
                                             att_ow + i * 256, Pbuf, sumexp);
        k5_att<<<dstBlocks, b256, 0, stream>>>(offsC, srt_rowC, x4b, cst + i * 128,
                                               Pbuf, att16, sumexp);
    }
    k6pred<<<nodeBlocks, b256, 0, stream>>>(att16, sumexp, x4b, att_ob + 12, ln_g + 12,
                                            ln_b + 12, res_w + 3, xcur, in_w, in_b,
                                            out_w1, out_b1, out_w2, out_b2, (float*)d_out);
}